// Round 4
// baseline (3151.636 us; speedup 1.0000x reference)
//
#include <hip/hip_runtime.h>
#include <math.h>

// Problem constants (fixed by the reference)
constexpr int NN  = 50000;   // nodes
constexpr int NE  = 600000;  // edges
constexpr int D   = 128;     // DIM == HID
constexpr int IND = 392;     // 3*DIM + TEMB

__device__ __forceinline__ float4 ld4(const float* p) { return *reinterpret_cast<const float4*>(p); }
__device__ __forceinline__ void   st4(float* p, float4 v) { *reinterpret_cast<float4*>(p) = v; }

// ---------------------------------------------------------------------------
// GEMM tile core: C[32 rows][128 outs] += X[32][128k] * W[128 outs][128k]^T
// per-thread register tile: 2 rows x 8 outputs (16 acc regs -> fits VGPR=64
// with no spill). X in LDS (rows padded to 132 -> 2-way aliasing = free).
// W streamed from global (L2-resident, shared by all blocks).
// ---------------------------------------------------------------------------
__device__ __forceinline__ void gemm_tile(const float (*X)[132],
                                          const float* __restrict__ W, int ldw,
                                          int r0, int o0, float acc[2][8])
{
#pragma unroll 2
  for (int k = 0; k < 128; k += 4) {
    float4 x[2];
    x[0] = ld4(&X[r0][k]);
    x[1] = ld4(&X[r0 + 1][k]);
#pragma unroll
    for (int j = 0; j < 8; ++j) {
      float4 w = ld4(&W[(o0 + j) * ldw + k]);
#pragma unroll
      for (int i = 0; i < 2; ++i) {
        acc[i][j] = fmaf(x[i].x, w.x, acc[i][j]);
        acc[i][j] = fmaf(x[i].y, w.y, acc[i][j]);
        acc[i][j] = fmaf(x[i].z, w.z, acc[i][j]);
        acc[i][j] = fmaf(x[i].w, w.w, acc[i][j]);
      }
    }
  }
}

__device__ __forceinline__ void zero_acc(float acc[2][8]) {
#pragma unroll
  for (int i = 0; i < 2; ++i)
#pragma unroll
    for (int j = 0; j < 8; ++j) acc[i][j] = 0.0f;
}

// ---------------------------------------------------------------------------
// K1: per-node precompute. 32 nodes/block, acc[2][8], LDS ~17KB -> 8 blk/CU.
//   A[n]  = ew1[:,   0:128] . z[n]
//   B[n]  = ew1[:, 128:256] . z[n]
//   M[n]  = mw2 . relu(mw1 . z[n] + mb1) + mb2
// ---------------------------------------------------------------------------
__global__ __launch_bounds__(256, 4) void k_node(
    const float* __restrict__ z, const float* __restrict__ ew1,
    const float* __restrict__ mw1, const float* __restrict__ mb1,
    const float* __restrict__ mw2, const float* __restrict__ mb2,
    float* __restrict__ A, float* __restrict__ B, float* __restrict__ M)
{
  __shared__ float X[32][132];
  const int t  = threadIdx.x;
  const int n0 = blockIdx.x * 32;

#pragma unroll
  for (int c = 0; c < 4; ++c) {
    int f = c * 256 + t, r = f >> 5, c4 = f & 31;
    float4 v = make_float4(0.f, 0.f, 0.f, 0.f);
    if (n0 + r < NN) v = ld4(&z[(size_t)(n0 + r) * D + c4 * 4]);
    st4(&X[r][c4 * 4], v);
  }
  __syncthreads();

  const int r0 = (t >> 4) * 2;
  const int o0 = (t & 15) * 8;
  float acc[2][8];

  // ---- A ----
  zero_acc(acc);
  gemm_tile(X, ew1, IND, r0, o0, acc);
#pragma unroll
  for (int i = 0; i < 2; ++i) {
    int n = n0 + r0 + i;
    if (n < NN) {
      st4(&A[(size_t)n * D + o0],     make_float4(acc[i][0], acc[i][1], acc[i][2], acc[i][3]));
      st4(&A[(size_t)n * D + o0 + 4], make_float4(acc[i][4], acc[i][5], acc[i][6], acc[i][7]));
    }
  }

  // ---- B ----
  zero_acc(acc);
  gemm_tile(X, ew1 + 128, IND, r0, o0, acc);
#pragma unroll
  for (int i = 0; i < 2; ++i) {
    int n = n0 + r0 + i;
    if (n < NN) {
      st4(&B[(size_t)n * D + o0],     make_float4(acc[i][0], acc[i][1], acc[i][2], acc[i][3]));
      st4(&B[(size_t)n * D + o0 + 4], make_float4(acc[i][4], acc[i][5], acc[i][6], acc[i][7]));
    }
  }

  // ---- M layer 1: h1 = relu(mw1.z + mb1), swapped through LDS ----
  zero_acc(acc);
  gemm_tile(X, mw1, D, r0, o0, acc);
  __syncthreads();
#pragma unroll
  for (int i = 0; i < 2; ++i)
#pragma unroll
    for (int j = 0; j < 8; ++j)
      X[r0 + i][o0 + j] = fmaxf(acc[i][j] + mb1[o0 + j], 0.0f);
  __syncthreads();

  // ---- M layer 2 ----
  zero_acc(acc);
  gemm_tile(X, mw2, D, r0, o0, acc);
#pragma unroll
  for (int i = 0; i < 2; ++i) {
    int n = n0 + r0 + i;
    if (n < NN) {
      st4(&M[(size_t)n * D + o0],
          make_float4(acc[i][0] + mb2[o0 + 0], acc[i][1] + mb2[o0 + 1],
                      acc[i][2] + mb2[o0 + 2], acc[i][3] + mb2[o0 + 3]));
      st4(&M[(size_t)n * D + o0 + 4],
          make_float4(acc[i][4] + mb2[o0 + 4], acc[i][5] + mb2[o0 + 5],
                      acc[i][6] + mb2[o0 + 6], acc[i][7] + mb2[o0 + 7]));
    }
  }
}

// ---------------------------------------------------------------------------
// CSR build: histogram -> single-block scan -> fill (stores eid + dst)
// ---------------------------------------------------------------------------
__global__ __launch_bounds__(256) void k_hist(const int* __restrict__ ei,
                                              int* __restrict__ deg)
{
  int e = blockIdx.x * 256 + threadIdx.x;
  if (e < NE) atomicAdd(&deg[ei[e]], 1);
}

__global__ __launch_bounds__(1024) void k_scan(const int* __restrict__ deg,
                                               int* __restrict__ rowptr,
                                               int* __restrict__ cursor)
{
  __shared__ int ps[1024];
  const int t = threadIdx.x;
  const int CH = 49;  // 1024*49 = 50176 >= NN
  int lo = t * CH, hi = min(lo + CH, NN);
  if (lo > NN) { lo = NN; hi = NN; }
  int s = 0;
  for (int i = lo; i < hi; ++i) s += deg[i];
  ps[t] = s;
  __syncthreads();
  for (int off = 1; off < 1024; off <<= 1) {
    int v = (t >= off) ? ps[t - off] : 0;
    __syncthreads();
    ps[t] += v;
    __syncthreads();
  }
  int run = t ? ps[t - 1] : 0;
  for (int i = lo; i < hi; ++i) {
    rowptr[i] = run;
    cursor[i] = run;
    run += deg[i];
  }
  if (t == 1023) rowptr[NN] = NE;
}

__global__ __launch_bounds__(256) void k_fill(const int* __restrict__ ei,
                                              int* __restrict__ cursor,
                                              int* __restrict__ eid,
                                              int* __restrict__ de_perm)
{
  int e = blockIdx.x * 256 + threadIdx.x;
  if (e < NE) {
    int pos = atomicAdd(&cursor[ei[e]], 1);
    eid[pos] = e;
    de_perm[pos] = ei[NE + e];
  }
}

// ---------------------------------------------------------------------------
// K2: per-edge pass in CSR (src-sorted) order. 32 positions/block.
//   hc = Wc . |z[src]-z[dst]|
//   h  = relu(hc + A[src] + B[dst] + tvec[type] + eb1)
//   wexp_perm[pos] = exp(sigmoid(h . ew2 + eb2))
// src gathers ~sequential (L1-hot); B[dst] loaded in epilogue, latency hidden
// by 8 blocks/CU occupancy. No register prefetch -> no spills.
// ---------------------------------------------------------------------------
__global__ __launch_bounds__(256, 4) void k_edge(
    const float* __restrict__ z, const int* __restrict__ ei,
    const int* __restrict__ etype, const float* __restrict__ type_emb,
    const float* __restrict__ ew1, const float* __restrict__ eb1,
    const float* __restrict__ ew2, const float* __restrict__ eb2,
    const float* __restrict__ A, const float* __restrict__ B,
    const int* __restrict__ eid, const int* __restrict__ de_perm,
    float* __restrict__ wexp_perm)
{
  __shared__ float X[32][132];
  __shared__ float tv[2][128];
  __shared__ int   se[32], de[32], tye[32];

  const int t  = threadIdx.x;
  const int e0 = blockIdx.x * 32;

  // tv[ty][o] = sum_j ew1[o][384+j]*type_emb[ty][j]
  {
    int o = t & 127, ty = t >> 7;
    float s = 0.f;
#pragma unroll
    for (int j = 0; j < 8; ++j) s += ew1[o * IND + 384 + j] * type_emb[ty * 8 + j];
    tv[ty][o] = s;
  }
  if (t < 32) {
    int e = eid[e0 + t];
    se[t]  = ei[e];
    de[t]  = de_perm[e0 + t];
    tye[t] = etype[e];
  }
  __syncthreads();

  // stage |z[src]-z[dst]| (src rows L1-hot thanks to CSR order)
#pragma unroll
  for (int c = 0; c < 4; ++c) {
    int f = c * 256 + t, r = f >> 5, c4 = f & 31;
    float4 a = ld4(&z[(size_t)se[r] * D + c4 * 4]);
    float4 b = ld4(&z[(size_t)de[r] * D + c4 * 4]);
    st4(&X[r][c4 * 4], make_float4(fabsf(a.x - b.x), fabsf(a.y - b.y),
                                   fabsf(a.z - b.z), fabsf(a.w - b.w)));
  }
  __syncthreads();

  const int r0 = (t >> 4) * 2;
  const int o0 = (t & 15) * 8;
  float acc[2][8];
  zero_acc(acc);
  gemm_tile(X, ew1 + 256, IND, r0, o0, acc);  // Wc term

  // epilogue: finish h for my (2 edges x 8 outs), partial dot with ew2
  float4 c0 = ld4(&eb1[o0]), c1 = ld4(&eb1[o0 + 4]);
  float4 w0 = ld4(&ew2[o0]), w1 = ld4(&ew2[o0 + 4]);
  float p[2];
#pragma unroll
  for (int i = 0; i < 2; ++i) {
    int el = r0 + i;
    int s = se[el], dd = de[el], ty = tye[el];
    float4 a0 = ld4(&A[(size_t)s * D + o0]),  a1 = ld4(&A[(size_t)s * D + o0 + 4]);
    float4 b0 = ld4(&B[(size_t)dd * D + o0]), b1 = ld4(&B[(size_t)dd * D + o0 + 4]);
    float4 t0 = ld4(&tv[ty][o0]),             t1 = ld4(&tv[ty][o0 + 4]);
    float pp = 0.f, h;
    h = acc[i][0] + a0.x + b0.x + t0.x + c0.x; pp += fmaxf(h, 0.f) * w0.x;
    h = acc[i][1] + a0.y + b0.y + t0.y + c0.y; pp += fmaxf(h, 0.f) * w0.y;
    h = acc[i][2] + a0.z + b0.z + t0.z + c0.z; pp += fmaxf(h, 0.f) * w0.z;
    h = acc[i][3] + a0.w + b0.w + t0.w + c0.w; pp += fmaxf(h, 0.f) * w0.w;
    h = acc[i][4] + a1.x + b1.x + t1.x + c1.x; pp += fmaxf(h, 0.f) * w1.x;
    h = acc[i][5] + a1.y + b1.y + t1.y + c1.y; pp += fmaxf(h, 0.f) * w1.y;
    h = acc[i][6] + a1.z + b1.z + t1.z + c1.z; pp += fmaxf(h, 0.f) * w1.z;
    h = acc[i][7] + a1.w + b1.w + t1.w + c1.w; pp += fmaxf(h, 0.f) * w1.w;
    p[i] = pp;
  }

  // reduce over the 16 o-groups
#pragma unroll
  for (int m = 1; m < 16; m <<= 1) {
    p[0] += __shfl_xor(p[0], m);
    p[1] += __shfl_xor(p[1], m);
  }
  if ((t & 15) == 0) {
    float b2 = eb2[0];
#pragma unroll
    for (int i = 0; i < 2; ++i) {
      float w = 1.0f / (1.0f + expf(-(p[i] + b2)));  // sigmoid
      wexp_perm[e0 + r0 + i] = expf(w);              // w in (0,1): no max needed
    }
  }
}

// ---------------------------------------------------------------------------
// K3: fused per-node aggregation + residual + LayerNorm. One wave per node.
// wexp_perm is contiguous per node (CSR); de_perm gives dst directly.
// ---------------------------------------------------------------------------
__global__ __launch_bounds__(256) void k_agg(
    const float* __restrict__ z, const float* __restrict__ wexp_perm,
    const float* __restrict__ M, const int* __restrict__ rowptr,
    const int* __restrict__ eid, const int* __restrict__ de_perm,
    const float* __restrict__ gamma, const float* __restrict__ beta,
    float* __restrict__ out, float* __restrict__ alpha_out)
{
  const int t = threadIdx.x;
  const int n = blockIdx.x * 4 + (t >> 6);
  const int l = t & 63;
  const int start = rowptr[n], end = rowptr[n + 1];
  const float2* M2 = reinterpret_cast<const float2*>(M);

  // pass 1: total wexp over the node's edges (contiguous reads)
  float tot = 0.f;
  for (int base = start; base < end; base += 64) {
    if (base + l < end) tot += wexp_perm[base + l];
  }
#pragma unroll
  for (int off = 32; off; off >>= 1) tot += __shfl_xor(tot, off);
  const float inv = 1.0f / (tot + 1e-12f);

  // pass 2: alpha + weighted aggregation of M[dst]
  float2 acc = make_float2(0.f, 0.f);
  for (int base = start; base < end; base += 64) {
    int cnt = min(64, end - base);
    int dd = 0;
    float al = 0.f;
    if (l < cnt) {
      int pos = base + l;
      al = wexp_perm[pos] * inv;
      dd = de_perm[pos];
      alpha_out[eid[pos]] = al;
    }
    for (int i = 0; i < cnt; ++i) {
      float a = __shfl(al, i);
      int   d = __shfl(dd, i);
      float2 m = M2[(size_t)d * 64 + l];
      acc.x = fmaf(a, m.x, acc.x);
      acc.y = fmaf(a, m.y, acc.y);
    }
  }

  // residual + LayerNorm
  float2 xz = *reinterpret_cast<const float2*>(&z[(size_t)n * D + l * 2]);
  float x0 = xz.x + acc.x, x1 = xz.y + acc.y;
  float s = x0 + x1;
#pragma unroll
  for (int off = 32; off; off >>= 1) s += __shfl_xor(s, off);
  const float mu = s * (1.0f / 128.0f);
  float d0 = x0 - mu, d1 = x1 - mu;
  float q = d0 * d0 + d1 * d1;
#pragma unroll
  for (int off = 32; off; off >>= 1) q += __shfl_xor(q, off);
  const float rstd = rsqrtf(q * (1.0f / 128.0f) + 1e-5f);
  float2 g = *reinterpret_cast<const float2*>(&gamma[l * 2]);
  float2 b = *reinterpret_cast<const float2*>(&beta[l * 2]);
  float2 o = make_float2(d0 * rstd * g.x + b.x, d1 * rstd * g.y + b.y);
  *reinterpret_cast<float2*>(&out[(size_t)n * D + l * 2]) = o;
}

// ---------------------------------------------------------------------------
extern "C" void kernel_launch(void* const* d_in, const int* in_sizes, int n_in,
                              void* d_out, int out_size, void* d_ws, size_t ws_size,
                              hipStream_t stream)
{
  const float* z        = (const float*)d_in[0];
  const int*   ei       = (const int*)d_in[1];   // [2,E]: src row, then dst row
  const int*   etype    = (const int*)d_in[2];
  const float* type_emb = (const float*)d_in[3];
  const float* ew1      = (const float*)d_in[4];
  const float* eb1      = (const float*)d_in[5];
  const float* ew2      = (const float*)d_in[6];
  const float* eb2      = (const float*)d_in[7];
  const float* mw1      = (const float*)d_in[8];
  const float* mb1      = (const float*)d_in[9];
  const float* mw2      = (const float*)d_in[10];
  const float* mb2      = (const float*)d_in[11];
  const float* gamma    = (const float*)d_in[12];
  const float* beta     = (const float*)d_in[13];

  // workspace: A | B | M | wexp_perm (f32) || deg | rowptr | cursor | eid | de_perm (int)
  float* ws        = (float*)d_ws;
  float* A         = ws;
  float* B         = ws + 6400000;
  float* M         = ws + 12800000;
  float* wexp_perm = ws + 19200000;
  int*   deg       = (int*)(ws + 19800000);
  int*   rowptr    = deg + 50000;
  int*   cursor    = rowptr + 50004;
  int*   eid       = cursor + 50000;
  int*   de_perm   = eid + 600000;

  float* out       = (float*)d_out;
  float* alpha_out = out + (size_t)NN * D;

  hipMemsetAsync(deg, 0, 50000 * sizeof(int), stream);

  k_hist<<<(NE + 255) / 256, 256, 0, stream>>>(ei, deg);
  k_scan<<<1, 1024, 0, stream>>>(deg, rowptr, cursor);
  k_fill<<<(NE + 255) / 256, 256, 0, stream>>>(ei, cursor, eid, de_perm);
  k_node<<<(NN + 31) / 32, 256, 0, stream>>>(z, ew1, mw1, mb1, mw2, mb2, A, B, M);
  k_edge<<<NE / 32, 256, 0, stream>>>(z, ei, etype, type_emb, ew1, eb1, ew2, eb2,
                                      A, B, eid, de_perm, wexp_perm);
  k_agg<<<NN / 4, 256, 0, stream>>>(z, wexp_perm, M, rowptr, eid, de_perm,
                                    gamma, beta, out, alpha_out);
}

// Round 5
// 1783.028 us; speedup vs baseline: 1.7676x; 1.7676x over previous
//
#include <hip/hip_runtime.h>
#include <math.h>

// Problem constants (fixed by the reference)
constexpr int NN  = 50000;   // nodes
constexpr int NE  = 600000;  // edges
constexpr int D   = 128;     // DIM == HID
constexpr int IND = 392;     // 3*DIM + TEMB

__device__ __forceinline__ float4 ld4(const float* p) { return *reinterpret_cast<const float4*>(p); }
__device__ __forceinline__ void   st4(float* p, float4 v) { *reinterpret_cast<float4*>(p) = v; }

// float -> bf16 (RNE) and back, manual (no dtype dependence on hip_bf16 types)
__device__ __forceinline__ unsigned short f2bf(float f) {
  unsigned int u = __float_as_uint(f);
  u += 0x7fffu + ((u >> 16) & 1u);
  return (unsigned short)(u >> 16);
}
__device__ __forceinline__ float bf2f(unsigned short s) {
  return __uint_as_float(((unsigned int)s) << 16);
}

// ---------------------------------------------------------------------------
// GEMM tile core: C[64 rows][128 outs] += X[64][128k] * W[128 outs][128k]^T
// per-thread register tile: 4 rows x 8 outputs, j-loop split in 2x4 so only
// 4 W-float4 are live at once (acc 32 + x 16 + w 16 + addr ~= 80 VGPR).
// X in LDS (rows padded to 132 -> 2-way aliasing = free). W streamed from
// global (64KB, L1/L2-resident, amortized over 64 rows).
// ---------------------------------------------------------------------------
__device__ __forceinline__ void gemm_tile(const float (*X)[132],
                                          const float* __restrict__ W, int ldw,
                                          int r0, int o0, float acc[4][8])
{
#pragma unroll 2
  for (int k = 0; k < 128; k += 4) {
    float4 x[4];
#pragma unroll
    for (int i = 0; i < 4; ++i) x[i] = ld4(&X[r0 + i][k]);
    // j = 0..3
    {
      float4 w0 = ld4(&W[(o0 + 0) * ldw + k]);
      float4 w1 = ld4(&W[(o0 + 1) * ldw + k]);
      float4 w2 = ld4(&W[(o0 + 2) * ldw + k]);
      float4 w3 = ld4(&W[(o0 + 3) * ldw + k]);
#pragma unroll
      for (int i = 0; i < 4; ++i) {
        acc[i][0] = fmaf(x[i].x, w0.x, acc[i][0]); acc[i][0] = fmaf(x[i].y, w0.y, acc[i][0]);
        acc[i][0] = fmaf(x[i].z, w0.z, acc[i][0]); acc[i][0] = fmaf(x[i].w, w0.w, acc[i][0]);
        acc[i][1] = fmaf(x[i].x, w1.x, acc[i][1]); acc[i][1] = fmaf(x[i].y, w1.y, acc[i][1]);
        acc[i][1] = fmaf(x[i].z, w1.z, acc[i][1]); acc[i][1] = fmaf(x[i].w, w1.w, acc[i][1]);
        acc[i][2] = fmaf(x[i].x, w2.x, acc[i][2]); acc[i][2] = fmaf(x[i].y, w2.y, acc[i][2]);
        acc[i][2] = fmaf(x[i].z, w2.z, acc[i][2]); acc[i][2] = fmaf(x[i].w, w2.w, acc[i][2]);
        acc[i][3] = fmaf(x[i].x, w3.x, acc[i][3]); acc[i][3] = fmaf(x[i].y, w3.y, acc[i][3]);
        acc[i][3] = fmaf(x[i].z, w3.z, acc[i][3]); acc[i][3] = fmaf(x[i].w, w3.w, acc[i][3]);
      }
    }
    // j = 4..7
    {
      float4 w0 = ld4(&W[(o0 + 4) * ldw + k]);
      float4 w1 = ld4(&W[(o0 + 5) * ldw + k]);
      float4 w2 = ld4(&W[(o0 + 6) * ldw + k]);
      float4 w3 = ld4(&W[(o0 + 7) * ldw + k]);
#pragma unroll
      for (int i = 0; i < 4; ++i) {
        acc[i][4] = fmaf(x[i].x, w0.x, acc[i][4]); acc[i][4] = fmaf(x[i].y, w0.y, acc[i][4]);
        acc[i][4] = fmaf(x[i].z, w0.z, acc[i][4]); acc[i][4] = fmaf(x[i].w, w0.w, acc[i][4]);
        acc[i][5] = fmaf(x[i].x, w1.x, acc[i][5]); acc[i][5] = fmaf(x[i].y, w1.y, acc[i][5]);
        acc[i][5] = fmaf(x[i].z, w1.z, acc[i][5]); acc[i][5] = fmaf(x[i].w, w1.w, acc[i][5]);
        acc[i][6] = fmaf(x[i].x, w2.x, acc[i][6]); acc[i][6] = fmaf(x[i].y, w2.y, acc[i][6]);
        acc[i][6] = fmaf(x[i].z, w2.z, acc[i][6]); acc[i][6] = fmaf(x[i].w, w2.w, acc[i][6]);
        acc[i][7] = fmaf(x[i].x, w3.x, acc[i][7]); acc[i][7] = fmaf(x[i].y, w3.y, acc[i][7]);
        acc[i][7] = fmaf(x[i].z, w3.z, acc[i][7]); acc[i][7] = fmaf(x[i].w, w3.w, acc[i][7]);
      }
    }
  }
}

__device__ __forceinline__ void zero_acc(float acc[4][8]) {
#pragma unroll
  for (int i = 0; i < 4; ++i)
#pragma unroll
    for (int j = 0; j < 8; ++j) acc[i][j] = 0.0f;
}

// ---------------------------------------------------------------------------
// K1: per-node precompute. 64 nodes/block.
//   A[n]  = ew1[:,   0:128] . z[n]         (f32)
//   B[n]  = ew1[:, 128:256] . z[n]         (f32)
//   Mb[n] = bf16( mw2 . relu(mw1 . z[n] + mb1) + mb2 )
// ---------------------------------------------------------------------------
__global__ __launch_bounds__(256, 2) void k_node(
    const float* __restrict__ z, const float* __restrict__ ew1,
    const float* __restrict__ mw1, const float* __restrict__ mb1,
    const float* __restrict__ mw2, const float* __restrict__ mb2,
    float* __restrict__ A, float* __restrict__ B, unsigned short* __restrict__ Mb)
{
  __shared__ float X[64][132];
  const int t  = threadIdx.x;
  const int n0 = blockIdx.x * 64;

#pragma unroll
  for (int c = 0; c < 8; ++c) {
    int f = c * 256 + t, r = f >> 5, c4 = f & 31;
    float4 v = make_float4(0.f, 0.f, 0.f, 0.f);
    if (n0 + r < NN) v = ld4(&z[(size_t)(n0 + r) * D + c4 * 4]);
    st4(&X[r][c4 * 4], v);
  }
  __syncthreads();

  const int r0 = (t >> 4) * 4;
  const int o0 = (t & 15) * 8;
  float acc[4][8];

  // ---- A ----
  zero_acc(acc);
  gemm_tile(X, ew1, IND, r0, o0, acc);
#pragma unroll
  for (int i = 0; i < 4; ++i) {
    int n = n0 + r0 + i;
    if (n < NN) {
      st4(&A[(size_t)n * D + o0],     make_float4(acc[i][0], acc[i][1], acc[i][2], acc[i][3]));
      st4(&A[(size_t)n * D + o0 + 4], make_float4(acc[i][4], acc[i][5], acc[i][6], acc[i][7]));
    }
  }

  // ---- B ----
  zero_acc(acc);
  gemm_tile(X, ew1 + 128, IND, r0, o0, acc);
#pragma unroll
  for (int i = 0; i < 4; ++i) {
    int n = n0 + r0 + i;
    if (n < NN) {
      st4(&B[(size_t)n * D + o0],     make_float4(acc[i][0], acc[i][1], acc[i][2], acc[i][3]));
      st4(&B[(size_t)n * D + o0 + 4], make_float4(acc[i][4], acc[i][5], acc[i][6], acc[i][7]));
    }
  }

  // ---- M layer 1: h1 = relu(mw1.z + mb1), swapped through LDS ----
  zero_acc(acc);
  gemm_tile(X, mw1, D, r0, o0, acc);
  __syncthreads();
#pragma unroll
  for (int i = 0; i < 4; ++i)
#pragma unroll
    for (int j = 0; j < 8; ++j)
      X[r0 + i][o0 + j] = fmaxf(acc[i][j] + mb1[o0 + j], 0.0f);
  __syncthreads();

  // ---- M layer 2, stored bf16 ----
  zero_acc(acc);
  gemm_tile(X, mw2, D, r0, o0, acc);
#pragma unroll
  for (int i = 0; i < 4; ++i) {
    int n = n0 + r0 + i;
    if (n < NN) {
      ushort4 v0, v1;
      v0.x = f2bf(acc[i][0] + mb2[o0 + 0]); v0.y = f2bf(acc[i][1] + mb2[o0 + 1]);
      v0.z = f2bf(acc[i][2] + mb2[o0 + 2]); v0.w = f2bf(acc[i][3] + mb2[o0 + 3]);
      v1.x = f2bf(acc[i][4] + mb2[o0 + 4]); v1.y = f2bf(acc[i][5] + mb2[o0 + 5]);
      v1.z = f2bf(acc[i][6] + mb2[o0 + 6]); v1.w = f2bf(acc[i][7] + mb2[o0 + 7]);
      *reinterpret_cast<ushort4*>(&Mb[(size_t)n * D + o0])     = v0;
      *reinterpret_cast<ushort4*>(&Mb[(size_t)n * D + o0 + 4]) = v1;
    }
  }
}

// ---------------------------------------------------------------------------
// CSR build: histogram -> single-block scan -> fill (stores eid + dst)
// ---------------------------------------------------------------------------
__global__ __launch_bounds__(256) void k_hist(const int* __restrict__ ei,
                                              int* __restrict__ deg)
{
  int e = blockIdx.x * 256 + threadIdx.x;
  if (e < NE) atomicAdd(&deg[ei[e]], 1);
}

__global__ __launch_bounds__(1024) void k_scan(const int* __restrict__ deg,
                                               int* __restrict__ rowptr,
                                               int* __restrict__ cursor)
{
  __shared__ int ps[1024];
  const int t = threadIdx.x;
  const int CH = 49;  // 1024*49 = 50176 >= NN
  int lo = t * CH, hi = min(lo + CH, NN);
  if (lo > NN) { lo = NN; hi = NN; }
  int s = 0;
  for (int i = lo; i < hi; ++i) s += deg[i];
  ps[t] = s;
  __syncthreads();
  for (int off = 1; off < 1024; off <<= 1) {
    int v = (t >= off) ? ps[t - off] : 0;
    __syncthreads();
    ps[t] += v;
    __syncthreads();
  }
  int run = t ? ps[t - 1] : 0;
  for (int i = lo; i < hi; ++i) {
    rowptr[i] = run;
    cursor[i] = run;
    run += deg[i];
  }
  if (t == 1023) rowptr[NN] = NE;
}

__global__ __launch_bounds__(256) void k_fill(const int* __restrict__ ei,
                                              int* __restrict__ cursor,
                                              int* __restrict__ eid,
                                              int* __restrict__ de_perm)
{
  int e = blockIdx.x * 256 + threadIdx.x;
  if (e < NE) {
    int pos = atomicAdd(&cursor[ei[e]], 1);
    eid[pos] = e;
    de_perm[pos] = ei[NE + e];
  }
}

// ---------------------------------------------------------------------------
// K2: per-edge pass in CSR (src-sorted) order. 64 positions/block.
//   hc = Wc . |z[src]-z[dst]|
//   h  = relu(hc + A[src] + B[dst] + tvec[type] + eb1)
//   wexp_perm[pos] = exp(sigmoid(h . ew2 + eb2))
// ---------------------------------------------------------------------------
__global__ __launch_bounds__(256, 2) void k_edge(
    const float* __restrict__ z, const int* __restrict__ ei,
    const int* __restrict__ etype, const float* __restrict__ type_emb,
    const float* __restrict__ ew1, const float* __restrict__ eb1,
    const float* __restrict__ ew2, const float* __restrict__ eb2,
    const float* __restrict__ A, const float* __restrict__ B,
    const int* __restrict__ eid, const int* __restrict__ de_perm,
    float* __restrict__ wexp_perm)
{
  __shared__ float X[64][132];
  __shared__ float tv[2][128];
  __shared__ int   se[64], de[64], tye[64];

  const int t  = threadIdx.x;
  const int e0 = blockIdx.x * 64;

  // tv[ty][o] = sum_j ew1[o][384+j]*type_emb[ty][j]
  {
    int o = t & 127, ty = t >> 7;
    float s = 0.f;
#pragma unroll
    for (int j = 0; j < 8; ++j) s += ew1[o * IND + 384 + j] * type_emb[ty * 8 + j];
    tv[ty][o] = s;
  }
  if (t < 64) {
    int e = eid[e0 + t];
    se[t]  = ei[e];
    de[t]  = de_perm[e0 + t];
    tye[t] = etype[e];
  }
  __syncthreads();

  // stage |z[src]-z[dst]| (src rows L1-hot thanks to CSR order)
#pragma unroll
  for (int c = 0; c < 8; ++c) {
    int f = c * 256 + t, r = f >> 5, c4 = f & 31;
    float4 a = ld4(&z[(size_t)se[r] * D + c4 * 4]);
    float4 b = ld4(&z[(size_t)de[r] * D + c4 * 4]);
    st4(&X[r][c4 * 4], make_float4(fabsf(a.x - b.x), fabsf(a.y - b.y),
                                   fabsf(a.z - b.z), fabsf(a.w - b.w)));
  }
  __syncthreads();

  const int r0 = (t >> 4) * 4;
  const int o0 = (t & 15) * 8;
  float acc[4][8];
  zero_acc(acc);
  gemm_tile(X, ew1 + 256, IND, r0, o0, acc);  // Wc term

  // epilogue: finish h for my (4 edges x 8 outs), partial dot with ew2
  float4 c0 = ld4(&eb1[o0]), c1 = ld4(&eb1[o0 + 4]);
  float4 w0 = ld4(&ew2[o0]), w1 = ld4(&ew2[o0 + 4]);
  float p[4];
#pragma unroll
  for (int i = 0; i < 4; ++i) {
    int el = r0 + i;
    int s = se[el], dd = de[el], ty = tye[el];
    float4 a0 = ld4(&A[(size_t)s * D + o0]),  a1 = ld4(&A[(size_t)s * D + o0 + 4]);
    float4 b0 = ld4(&B[(size_t)dd * D + o0]), b1 = ld4(&B[(size_t)dd * D + o0 + 4]);
    float4 t0 = ld4(&tv[ty][o0]),             t1 = ld4(&tv[ty][o0 + 4]);
    float pp = 0.f, h;
    h = acc[i][0] + a0.x + b0.x + t0.x + c0.x; pp += fmaxf(h, 0.f) * w0.x;
    h = acc[i][1] + a0.y + b0.y + t0.y + c0.y; pp += fmaxf(h, 0.f) * w0.y;
    h = acc[i][2] + a0.z + b0.z + t0.z + c0.z; pp += fmaxf(h, 0.f) * w0.z;
    h = acc[i][3] + a0.w + b0.w + t0.w + c0.w; pp += fmaxf(h, 0.f) * w0.w;
    h = acc[i][4] + a1.x + b1.x + t1.x + c1.x; pp += fmaxf(h, 0.f) * w1.x;
    h = acc[i][5] + a1.y + b1.y + t1.y + c1.y; pp += fmaxf(h, 0.f) * w1.y;
    h = acc[i][6] + a1.z + b1.z + t1.z + c1.z; pp += fmaxf(h, 0.f) * w1.z;
    h = acc[i][7] + a1.w + b1.w + t1.w + c1.w; pp += fmaxf(h, 0.f) * w1.w;
    p[i] = pp;
  }

  // reduce over the 16 o-groups
#pragma unroll
  for (int m = 1; m < 16; m <<= 1) {
#pragma unroll
    for (int i = 0; i < 4; ++i) p[i] += __shfl_xor(p[i], m);
  }
  if ((t & 15) == 0) {
    float b2 = eb2[0];
#pragma unroll
    for (int i = 0; i < 4; ++i) {
      float w = 1.0f / (1.0f + expf(-(p[i] + b2)));  // sigmoid
      wexp_perm[e0 + r0 + i] = expf(w);              // w in (0,1): no max needed
    }
  }
}

// ---------------------------------------------------------------------------
// K3: fused per-node aggregation + residual + LayerNorm. One wave per node.
// wexp_perm contiguous per node (CSR); Mb is bf16 (256B/row random gather).
// ---------------------------------------------------------------------------
__global__ __launch_bounds__(256) void k_agg(
    const float* __restrict__ z, const float* __restrict__ wexp_perm,
    const unsigned short* __restrict__ Mb, const int* __restrict__ rowptr,
    const int* __restrict__ eid, const int* __restrict__ de_perm,
    const float* __restrict__ gamma, const float* __restrict__ beta,
    float* __restrict__ out, float* __restrict__ alpha_out)
{
  const int t = threadIdx.x;
  const int n = blockIdx.x * 4 + (t >> 6);
  const int l = t & 63;
  const int start = rowptr[n], end = rowptr[n + 1];

  // pass 1: total wexp over the node's edges (contiguous reads)
  float tot = 0.f;
  for (int base = start; base < end; base += 64) {
    if (base + l < end) tot += wexp_perm[base + l];
  }
#pragma unroll
  for (int off = 32; off; off >>= 1) tot += __shfl_xor(tot, off);
  const float inv = 1.0f / (tot + 1e-12f);

  // pass 2: alpha + weighted aggregation of Mb[dst]
  float2 acc = make_float2(0.f, 0.f);
  for (int base = start; base < end; base += 64) {
    int cnt = min(64, end - base);
    int dd = 0;
    float al = 0.f;
    if (l < cnt) {
      int pos = base + l;
      al = wexp_perm[pos] * inv;
      dd = de_perm[pos];
      alpha_out[eid[pos]] = al;
    }
    for (int i = 0; i < cnt; ++i) {
      float a = __shfl(al, i);
      int   d = __shfl(dd, i);
      ushort2 m = *reinterpret_cast<const ushort2*>(&Mb[(size_t)d * D + l * 2]);
      acc.x = fmaf(a, bf2f(m.x), acc.x);
      acc.y = fmaf(a, bf2f(m.y), acc.y);
    }
  }

  // residual + LayerNorm
  float2 xz = *reinterpret_cast<const float2*>(&z[(size_t)n * D + l * 2]);
  float x0 = xz.x + acc.x, x1 = xz.y + acc.y;
  float s = x0 + x1;
#pragma unroll
  for (int off = 32; off; off >>= 1) s += __shfl_xor(s, off);
  const float mu = s * (1.0f / 128.0f);
  float d0 = x0 - mu, d1 = x1 - mu;
  float q = d0 * d0 + d1 * d1;
#pragma unroll
  for (int off = 32; off; off >>= 1) q += __shfl_xor(q, off);
  const float rstd = rsqrtf(q * (1.0f / 128.0f) + 1e-5f);
  float2 g = *reinterpret_cast<const float2*>(&gamma[l * 2]);
  float2 b = *reinterpret_cast<const float2*>(&beta[l * 2]);
  float2 o = make_float2(d0 * rstd * g.x + b.x, d1 * rstd * g.y + b.y);
  *reinterpret_cast<float2*>(&out[(size_t)n * D + l * 2]) = o;
}

// ---------------------------------------------------------------------------
extern "C" void kernel_launch(void* const* d_in, const int* in_sizes, int n_in,
                              void* d_out, int out_size, void* d_ws, size_t ws_size,
                              hipStream_t stream)
{
  const float* z        = (const float*)d_in[0];
  const int*   ei       = (const int*)d_in[1];   // [2,E]: src row, then dst row
  const int*   etype    = (const int*)d_in[2];
  const float* type_emb = (const float*)d_in[3];
  const float* ew1      = (const float*)d_in[4];
  const float* eb1      = (const float*)d_in[5];
  const float* ew2      = (const float*)d_in[6];
  const float* eb2      = (const float*)d_in[7];
  const float* mw1      = (const float*)d_in[8];
  const float* mb1      = (const float*)d_in[9];
  const float* mw2      = (const float*)d_in[10];
  const float* mb2      = (const float*)d_in[11];
  const float* gamma    = (const float*)d_in[12];
  const float* beta     = (const float*)d_in[13];

  // workspace: A | B (f32) | Mb (bf16) | wexp_perm (f32) || deg | rowptr | cursor | eid | de_perm
  float*          ws        = (float*)d_ws;
  float*          A         = ws;
  float*          B         = ws + 6400000;
  unsigned short* Mb        = (unsigned short*)(ws + 12800000);  // 6.4M ushort = 3.2M f32 slots
  float*          wexp_perm = ws + 16000000;
  int*            deg       = (int*)(ws + 16600000);
  int*            rowptr    = deg + 50000;
  int*            cursor    = rowptr + 50004;
  int*            eid       = cursor + 50000;
  int*            de_perm   = eid + 600000;

  float* out       = (float*)d_out;
  float* alpha_out = out + (size_t)NN * D;

  hipMemsetAsync(deg, 0, 50000 * sizeof(int), stream);

  k_hist<<<(NE + 255) / 256, 256, 0, stream>>>(ei, deg);
  k_scan<<<1, 1024, 0, stream>>>(deg, rowptr, cursor);
  k_fill<<<(NE + 255) / 256, 256, 0, stream>>>(ei, cursor, eid, de_perm);
  k_node<<<(NN + 63) / 64, 256, 0, stream>>>(z, ew1, mw1, mb1, mw2, mb2, A, B, Mb);
  k_edge<<<NE / 64, 256, 0, stream>>>(z, ei, etype, type_emb, ew1, eb1, ew2, eb2,
                                      A, B, eid, de_perm, wexp_perm);
  k_agg<<<NN / 4, 256, 0, stream>>>(z, wexp_perm, Mb, rowptr, eid, de_perm,
                                    gamma, beta, out, alpha_out);
}

// Round 6
// 808.992 us; speedup vs baseline: 3.8958x; 2.2040x over previous
//
#include <hip/hip_runtime.h>
#include <math.h>

// Problem constants (fixed by the reference)
constexpr int NN  = 50000;   // nodes
constexpr int NE  = 600000;  // edges
constexpr int D   = 128;     // DIM == HID
constexpr int IND = 392;     // 3*DIM + TEMB

typedef __attribute__((ext_vector_type(8))) short bf16x8;   // 8 bf16 = 4 VGPR
typedef __attribute__((ext_vector_type(4))) float f32x4;    // MFMA accumulator

__device__ __forceinline__ float4 ld4(const float* p) { return *reinterpret_cast<const float4*>(p); }
__device__ __forceinline__ void   st4(float* p, float4 v) { *reinterpret_cast<float4*>(p) = v; }

// float -> bf16 (RNE) and back
__device__ __forceinline__ unsigned short f2bf(float f) {
  unsigned int u = __float_as_uint(f);
  u += 0x7fffu + ((u >> 16) & 1u);
  return (unsigned short)(u >> 16);
}
__device__ __forceinline__ float bf2f(unsigned short s) {
  return __uint_as_float(((unsigned int)s) << 16);
}

// ---------------------------------------------------------------------------
// fp32 GEMM tile core for k_node (unchanged from round 5).
// ---------------------------------------------------------------------------
__device__ __forceinline__ void gemm_tile(const float (*X)[132],
                                          const float* __restrict__ W, int ldw,
                                          int r0, int o0, float acc[4][8])
{
#pragma unroll 2
  for (int k = 0; k < 128; k += 4) {
    float4 x[4];
#pragma unroll
    for (int i = 0; i < 4; ++i) x[i] = ld4(&X[r0 + i][k]);
    {
      float4 w0 = ld4(&W[(o0 + 0) * ldw + k]);
      float4 w1 = ld4(&W[(o0 + 1) * ldw + k]);
      float4 w2 = ld4(&W[(o0 + 2) * ldw + k]);
      float4 w3 = ld4(&W[(o0 + 3) * ldw + k]);
#pragma unroll
      for (int i = 0; i < 4; ++i) {
        acc[i][0] = fmaf(x[i].x, w0.x, acc[i][0]); acc[i][0] = fmaf(x[i].y, w0.y, acc[i][0]);
        acc[i][0] = fmaf(x[i].z, w0.z, acc[i][0]); acc[i][0] = fmaf(x[i].w, w0.w, acc[i][0]);
        acc[i][1] = fmaf(x[i].x, w1.x, acc[i][1]); acc[i][1] = fmaf(x[i].y, w1.y, acc[i][1]);
        acc[i][1] = fmaf(x[i].z, w1.z, acc[i][1]); acc[i][1] = fmaf(x[i].w, w1.w, acc[i][1]);
        acc[i][2] = fmaf(x[i].x, w2.x, acc[i][2]); acc[i][2] = fmaf(x[i].y, w2.y, acc[i][2]);
        acc[i][2] = fmaf(x[i].z, w2.z, acc[i][2]); acc[i][2] = fmaf(x[i].w, w2.w, acc[i][2]);
        acc[i][3] = fmaf(x[i].x, w3.x, acc[i][3]); acc[i][3] = fmaf(x[i].y, w3.y, acc[i][3]);
        acc[i][3] = fmaf(x[i].z, w3.z, acc[i][3]); acc[i][3] = fmaf(x[i].w, w3.w, acc[i][3]);
      }
    }
    {
      float4 w0 = ld4(&W[(o0 + 4) * ldw + k]);
      float4 w1 = ld4(&W[(o0 + 5) * ldw + k]);
      float4 w2 = ld4(&W[(o0 + 6) * ldw + k]);
      float4 w3 = ld4(&W[(o0 + 7) * ldw + k]);
#pragma unroll
      for (int i = 0; i < 4; ++i) {
        acc[i][4] = fmaf(x[i].x, w0.x, acc[i][4]); acc[i][4] = fmaf(x[i].y, w0.y, acc[i][4]);
        acc[i][4] = fmaf(x[i].z, w0.z, acc[i][4]); acc[i][4] = fmaf(x[i].w, w0.w, acc[i][4]);
        acc[i][5] = fmaf(x[i].x, w1.x, acc[i][5]); acc[i][5] = fmaf(x[i].y, w1.y, acc[i][5]);
        acc[i][5] = fmaf(x[i].z, w1.z, acc[i][5]); acc[i][5] = fmaf(x[i].w, w1.w, acc[i][5]);
        acc[i][6] = fmaf(x[i].x, w2.x, acc[i][6]); acc[i][6] = fmaf(x[i].y, w2.y, acc[i][6]);
        acc[i][6] = fmaf(x[i].z, w2.z, acc[i][6]); acc[i][6] = fmaf(x[i].w, w2.w, acc[i][6]);
        acc[i][7] = fmaf(x[i].x, w3.x, acc[i][7]); acc[i][7] = fmaf(x[i].y, w3.y, acc[i][7]);
        acc[i][7] = fmaf(x[i].z, w3.z, acc[i][7]); acc[i][7] = fmaf(x[i].w, w3.w, acc[i][7]);
      }
    }
  }
}

__device__ __forceinline__ void zero_acc(float acc[4][8]) {
#pragma unroll
  for (int i = 0; i < 4; ++i)
#pragma unroll
    for (int j = 0; j < 8; ++j) acc[i][j] = 0.0f;
}

// ---------------------------------------------------------------------------
// K0: pre-pass. Wcb = bf16(ew1[:,256:384]) [out][k]; tvg[ty][o] = Wt.type_emb
// ---------------------------------------------------------------------------
__global__ __launch_bounds__(256) void k_prep(
    const float* __restrict__ ew1, const float* __restrict__ type_emb,
    unsigned short* __restrict__ Wcb, float* __restrict__ tvg)
{
  int g = blockIdx.x * 256 + threadIdx.x;   // 0..16383
  int o = g >> 7, k = g & 127;
  Wcb[o * 128 + k] = f2bf(ew1[o * IND + 256 + k]);
  if (blockIdx.x == 0) {
    int t = threadIdx.x, oo = t & 127, ty = t >> 7;
    float s = 0.f;
#pragma unroll
    for (int j = 0; j < 8; ++j) s += ew1[oo * IND + 384 + j] * type_emb[ty * 8 + j];
    tvg[ty * 128 + oo] = s;
  }
}

// ---------------------------------------------------------------------------
// K1: per-node precompute (fp32 VALU path, unchanged).
// ---------------------------------------------------------------------------
__global__ __launch_bounds__(256, 2) void k_node(
    const float* __restrict__ z, const float* __restrict__ ew1,
    const float* __restrict__ mw1, const float* __restrict__ mb1,
    const float* __restrict__ mw2, const float* __restrict__ mb2,
    float* __restrict__ A, float* __restrict__ B, unsigned short* __restrict__ Mb)
{
  __shared__ float X[64][132];
  const int t  = threadIdx.x;
  const int n0 = blockIdx.x * 64;

#pragma unroll
  for (int c = 0; c < 8; ++c) {
    int f = c * 256 + t, r = f >> 5, c4 = f & 31;
    float4 v = make_float4(0.f, 0.f, 0.f, 0.f);
    if (n0 + r < NN) v = ld4(&z[(size_t)(n0 + r) * D + c4 * 4]);
    st4(&X[r][c4 * 4], v);
  }
  __syncthreads();

  const int r0 = (t >> 4) * 4;
  const int o0 = (t & 15) * 8;
  float acc[4][8];

  zero_acc(acc);
  gemm_tile(X, ew1, IND, r0, o0, acc);
#pragma unroll
  for (int i = 0; i < 4; ++i) {
    int n = n0 + r0 + i;
    if (n < NN) {
      st4(&A[(size_t)n * D + o0],     make_float4(acc[i][0], acc[i][1], acc[i][2], acc[i][3]));
      st4(&A[(size_t)n * D + o0 + 4], make_float4(acc[i][4], acc[i][5], acc[i][6], acc[i][7]));
    }
  }

  zero_acc(acc);
  gemm_tile(X, ew1 + 128, IND, r0, o0, acc);
#pragma unroll
  for (int i = 0; i < 4; ++i) {
    int n = n0 + r0 + i;
    if (n < NN) {
      st4(&B[(size_t)n * D + o0],     make_float4(acc[i][0], acc[i][1], acc[i][2], acc[i][3]));
      st4(&B[(size_t)n * D + o0 + 4], make_float4(acc[i][4], acc[i][5], acc[i][6], acc[i][7]));
    }
  }

  zero_acc(acc);
  gemm_tile(X, mw1, D, r0, o0, acc);
  __syncthreads();
#pragma unroll
  for (int i = 0; i < 4; ++i)
#pragma unroll
    for (int j = 0; j < 8; ++j)
      X[r0 + i][o0 + j] = fmaxf(acc[i][j] + mb1[o0 + j], 0.0f);
  __syncthreads();

  zero_acc(acc);
  gemm_tile(X, mw2, D, r0, o0, acc);
#pragma unroll
  for (int i = 0; i < 4; ++i) {
    int n = n0 + r0 + i;
    if (n < NN) {
      ushort4 v0, v1;
      v0.x = f2bf(acc[i][0] + mb2[o0 + 0]); v0.y = f2bf(acc[i][1] + mb2[o0 + 1]);
      v0.z = f2bf(acc[i][2] + mb2[o0 + 2]); v0.w = f2bf(acc[i][3] + mb2[o0 + 3]);
      v1.x = f2bf(acc[i][4] + mb2[o0 + 4]); v1.y = f2bf(acc[i][5] + mb2[o0 + 5]);
      v1.z = f2bf(acc[i][6] + mb2[o0 + 6]); v1.w = f2bf(acc[i][7] + mb2[o0 + 7]);
      *reinterpret_cast<ushort4*>(&Mb[(size_t)n * D + o0])     = v0;
      *reinterpret_cast<ushort4*>(&Mb[(size_t)n * D + o0 + 4]) = v1;
    }
  }
}

// ---------------------------------------------------------------------------
// CSR build: histogram -> single-block scan -> fill (stores eid + dst)
// ---------------------------------------------------------------------------
__global__ __launch_bounds__(256) void k_hist(const int* __restrict__ ei,
                                              int* __restrict__ deg)
{
  int e = blockIdx.x * 256 + threadIdx.x;
  if (e < NE) atomicAdd(&deg[ei[e]], 1);
}

__global__ __launch_bounds__(1024) void k_scan(const int* __restrict__ deg,
                                               int* __restrict__ rowptr,
                                               int* __restrict__ cursor)
{
  __shared__ int ps[1024];
  const int t = threadIdx.x;
  const int CH = 49;
  int lo = t * CH, hi = min(lo + CH, NN);
  if (lo > NN) { lo = NN; hi = NN; }
  int s = 0;
  for (int i = lo; i < hi; ++i) s += deg[i];
  ps[t] = s;
  __syncthreads();
  for (int off = 1; off < 1024; off <<= 1) {
    int v = (t >= off) ? ps[t - off] : 0;
    __syncthreads();
    ps[t] += v;
    __syncthreads();
  }
  int run = t ? ps[t - 1] : 0;
  for (int i = lo; i < hi; ++i) {
    rowptr[i] = run;
    cursor[i] = run;
    run += deg[i];
  }
  if (t == 1023) rowptr[NN] = NE;
}

__global__ __launch_bounds__(256) void k_fill(const int* __restrict__ ei,
                                              int* __restrict__ cursor,
                                              int* __restrict__ eid,
                                              int* __restrict__ de_perm)
{
  int e = blockIdx.x * 256 + threadIdx.x;
  if (e < NE) {
    int pos = atomicAdd(&cursor[ei[e]], 1);
    eid[pos] = e;
    de_perm[pos] = ei[NE + e];
  }
}

// ---------------------------------------------------------------------------
// K2: per-edge pass, bf16 MFMA. 128 edges/block, 8 waves, CSR order.
//   X = bf16(|z[src]-z[dst]|) in LDS [128][136]; Wc bf16 in LDS [128][136].
//   Wave w: 16-edge tile (me=w*16) x 128 outs via 8 n-tiles x 4 k-steps of
//   mfma_f32_16x16x32_bf16.  A-frag row=l&15,k=(l>>4)*8+i; B-frag from W
//   ([out][k] row-major = B^T, same fragment shape).  C/D: col=l&15 (out),
//   row=(l>>4)*4+reg (edge).
//   Epilogue: h = acc + A[src]+B[dst]+tv[ty]+eb1; p = sum relu(h)*ew2,
//   reduce over the 16 col-lanes, sigmoid -> exp -> wexp_perm.
// ---------------------------------------------------------------------------
__global__ __launch_bounds__(512, 4) void k_edge_mfma(
    const float* __restrict__ z, const int* __restrict__ ei,
    const int* __restrict__ etype,
    const unsigned short* __restrict__ Wcb, const float* __restrict__ tvg,
    const float* __restrict__ eb1, const float* __restrict__ ew2,
    const float* __restrict__ eb2,
    const float* __restrict__ A, const float* __restrict__ B,
    const int* __restrict__ eid, const int* __restrict__ de_perm,
    float* __restrict__ wexp_perm)
{
  __shared__ unsigned short Xb[128][136];  // pad 136 -> frag reads min-aliasing
  __shared__ unsigned short Wb[128][136];
  __shared__ int se[128], de[128], tye[128];

  const int t  = threadIdx.x;
  const int e0 = blockIdx.x * 128;

  if (t < 128) {
    int pos = e0 + t;
    if (pos < NE) {
      int e  = eid[pos];
      se[t]  = ei[e];
      de[t]  = de_perm[pos];
      tye[t] = etype[e];
    } else { se[t] = 0; de[t] = 0; tye[t] = 0; }
  }
  // stage Wc (bf16, 32KB) - coalesced 16B per thread-iter
#pragma unroll
  for (int it = 0; it < 4; ++it) {
    int f = it * 512 + t, row = f >> 4, c8 = (f & 15) * 8;
    *reinterpret_cast<bf16x8*>(&Wb[row][c8]) =
        *reinterpret_cast<const bf16x8*>(&Wcb[row * 128 + c8]);
  }
  __syncthreads();

  // stage |z[src]-z[dst]| as bf16 (src ~sequential in CSR order)
#pragma unroll
  for (int it = 0; it < 8; ++it) {
    int f = it * 512 + t, r = f >> 5, c4 = (f & 31) * 4;
    float4 a = ld4(&z[(size_t)se[r] * D + c4]);
    float4 b = ld4(&z[(size_t)de[r] * D + c4]);
    ushort4 v;
    v.x = f2bf(fabsf(a.x - b.x)); v.y = f2bf(fabsf(a.y - b.y));
    v.z = f2bf(fabsf(a.z - b.z)); v.w = f2bf(fabsf(a.w - b.w));
    *reinterpret_cast<ushort4*>(&Xb[r][c4]) = v;
  }
  __syncthreads();

  const int l = t & 63, q = l >> 4, r = l & 15;
  const int me = (t >> 6) * 16;   // wave's edge-tile base

  f32x4 acc[8];
#pragma unroll
  for (int nt = 0; nt < 8; ++nt) acc[nt] = (f32x4){0.f, 0.f, 0.f, 0.f};

#pragma unroll
  for (int ks = 0; ks < 4; ++ks) {
    bf16x8 a = *reinterpret_cast<const bf16x8*>(&Xb[me + r][ks * 32 + q * 8]);
#pragma unroll
    for (int nt = 0; nt < 8; ++nt) {
      bf16x8 b = *reinterpret_cast<const bf16x8*>(&Wb[nt * 16 + r][ks * 32 + q * 8]);
      acc[nt] = __builtin_amdgcn_mfma_f32_16x16x32_bf16(a, b, acc[nt], 0, 0, 0);
    }
  }

  // epilogue: my 4 edges are me+q*4+{0..3}; my out-columns are nt*16+r
  int s[4], dd[4], ty[4];
#pragma unroll
  for (int i = 0; i < 4; ++i) {
    int el = me + q * 4 + i;
    s[i] = se[el]; dd[i] = de[el]; ty[i] = tye[el];
  }
  float p[4] = {0.f, 0.f, 0.f, 0.f};
#pragma unroll
  for (int nt = 0; nt < 8; ++nt) {
    int col = nt * 16 + r;
    float e1  = eb1[col], w2 = ew2[col];
    float tva = tvg[col], tvb = tvg[128 + col];
#pragma unroll
    for (int i = 0; i < 4; ++i) {
      float h = acc[nt][i] + A[(size_t)s[i] * D + col] + B[(size_t)dd[i] * D + col]
              + (ty[i] ? tvb : tva) + e1;
      p[i] += fmaxf(h, 0.f) * w2;
    }
  }
#pragma unroll
  for (int m = 1; m < 16; m <<= 1) {
#pragma unroll
    for (int i = 0; i < 4; ++i) p[i] += __shfl_xor(p[i], m);
  }
  if (r == 0) {
    float b2 = eb2[0];
#pragma unroll
    for (int i = 0; i < 4; ++i) {
      int pos = e0 + me + q * 4 + i;
      if (pos < NE) {
        float w = 1.0f / (1.0f + expf(-(p[i] + b2)));  // sigmoid
        wexp_perm[pos] = expf(w);                      // w in (0,1): stable
      }
    }
  }
}

// ---------------------------------------------------------------------------
// K3: fused per-node aggregation + residual + LayerNorm (unchanged).
// ---------------------------------------------------------------------------
__global__ __launch_bounds__(256) void k_agg(
    const float* __restrict__ z, const float* __restrict__ wexp_perm,
    const unsigned short* __restrict__ Mb, const int* __restrict__ rowptr,
    const int* __restrict__ eid, const int* __restrict__ de_perm,
    const float* __restrict__ gamma, const float* __restrict__ beta,
    float* __restrict__ out, float* __restrict__ alpha_out)
{
  const int t = threadIdx.x;
  const int n = blockIdx.x * 4 + (t >> 6);
  const int l = t & 63;
  const int start = rowptr[n], end = rowptr[n + 1];

  float tot = 0.f;
  for (int base = start; base < end; base += 64) {
    if (base + l < end) tot += wexp_perm[base + l];
  }
#pragma unroll
  for (int off = 32; off; off >>= 1) tot += __shfl_xor(tot, off);
  const float inv = 1.0f / (tot + 1e-12f);

  float2 acc = make_float2(0.f, 0.f);
  for (int base = start; base < end; base += 64) {
    int cnt = min(64, end - base);
    int dd = 0;
    float al = 0.f;
    if (l < cnt) {
      int pos = base + l;
      al = wexp_perm[pos] * inv;
      dd = de_perm[pos];
      alpha_out[eid[pos]] = al;
    }
    for (int i = 0; i < cnt; ++i) {
      float a = __shfl(al, i);
      int   d = __shfl(dd, i);
      ushort2 m = *reinterpret_cast<const ushort2*>(&Mb[(size_t)d * D + l * 2]);
      acc.x = fmaf(a, bf2f(m.x), acc.x);
      acc.y = fmaf(a, bf2f(m.y), acc.y);
    }
  }

  float2 xz = *reinterpret_cast<const float2*>(&z[(size_t)n * D + l * 2]);
  float x0 = xz.x + acc.x, x1 = xz.y + acc.y;
  float s = x0 + x1;
#pragma unroll
  for (int off = 32; off; off >>= 1) s += __shfl_xor(s, off);
  const float mu = s * (1.0f / 128.0f);
  float d0 = x0 - mu, d1 = x1 - mu;
  float q = d0 * d0 + d1 * d1;
#pragma unroll
  for (int off = 32; off; off >>= 1) q += __shfl_xor(q, off);
  const float rstd = rsqrtf(q * (1.0f / 128.0f) + 1e-5f);
  float2 g = *reinterpret_cast<const float2*>(&gamma[l * 2]);
  float2 b = *reinterpret_cast<const float2*>(&beta[l * 2]);
  float2 o = make_float2(d0 * rstd * g.x + b.x, d1 * rstd * g.y + b.y);
  *reinterpret_cast<float2*>(&out[(size_t)n * D + l * 2]) = o;
}

// ---------------------------------------------------------------------------
extern "C" void kernel_launch(void* const* d_in, const int* in_sizes, int n_in,
                              void* d_out, int out_size, void* d_ws, size_t ws_size,
                              hipStream_t stream)
{
  const float* z        = (const float*)d_in[0];
  const int*   ei       = (const int*)d_in[1];   // [2,E]: src row, then dst row
  const int*   etype    = (const int*)d_in[2];
  const float* type_emb = (const float*)d_in[3];
  const float* ew1      = (const float*)d_in[4];
  const float* eb1      = (const float*)d_in[5];
  const float* ew2      = (const float*)d_in[6];
  const float* eb2      = (const float*)d_in[7];
  const float* mw1      = (const float*)d_in[8];
  const float* mb1      = (const float*)d_in[9];
  const float* mw2      = (const float*)d_in[10];
  const float* mb2      = (const float*)d_in[11];
  const float* gamma    = (const float*)d_in[12];
  const float* beta     = (const float*)d_in[13];

  // workspace: A | B (f32) | Mb (bf16) | wexp_perm || ints || Wcb (bf16) | tvg
  float*          ws        = (float*)d_ws;
  float*          A         = ws;
  float*          B         = ws + 6400000;
  unsigned short* Mb        = (unsigned short*)(ws + 12800000);
  float*          wexp_perm = ws + 16000000;
  int*            deg       = (int*)(ws + 16600000);
  int*            rowptr    = deg + 50000;
  int*            cursor    = rowptr + 50004;
  int*            eid       = cursor + 50000;
  int*            de_perm   = eid + 600000;
  unsigned short* Wcb       = (unsigned short*)(ws + 18000000);
  float*          tvg       = ws + 18100000;

  float* out       = (float*)d_out;
  float* alpha_out = out + (size_t)NN * D;

  hipMemsetAsync(deg, 0, 50000 * sizeof(int), stream);

  k_hist<<<(NE + 255) / 256, 256, 0, stream>>>(ei, deg);
  k_scan<<<1, 1024, 0, stream>>>(deg, rowptr, cursor);
  k_fill<<<(NE + 255) / 256, 256, 0, stream>>>(ei, cursor, eid, de_perm);
  k_prep<<<64, 256, 0, stream>>>(ew1, type_emb, Wcb, tvg);
  k_node<<<(NN + 63) / 64, 256, 0, stream>>>(z, ew1, mw1, mb1, mw2, mb2, A, B, Mb);
  k_edge_mfma<<<(NE + 127) / 128, 512, 0, stream>>>(z, ei, etype, Wcb, tvg,
                                                    eb1, ew2, eb2, A, B,
                                                    eid, de_perm, wexp_perm);
  k_agg<<<NN / 4, 256, 0, stream>>>(z, wexp_perm, Mb, rowptr, eid, de_perm,
                                    gamma, beta, out, alpha_out);
}

// Round 7
// 388.801 us; speedup vs baseline: 8.1060x; 2.0807x over previous
//
#include <hip/hip_runtime.h>
#include <math.h>

// Problem constants (fixed by the reference)
constexpr int NN  = 50000;   // nodes
constexpr int NE  = 600000;  // edges
constexpr int D   = 128;     // DIM == HID
constexpr int IND = 392;     // 3*DIM + TEMB

typedef __attribute__((ext_vector_type(8))) short bf16x8;   // 8 bf16 = 4 VGPR
typedef __attribute__((ext_vector_type(4))) float f32x4;    // MFMA accumulator

__device__ __forceinline__ float4 ld4(const float* p) { return *reinterpret_cast<const float4*>(p); }
__device__ __forceinline__ void   st4(float* p, float4 v) { *reinterpret_cast<float4*>(p) = v; }

// float -> bf16 (RNE) and back
__device__ __forceinline__ unsigned short f2bf(float f) {
  unsigned int u = __float_as_uint(f);
  u += 0x7fffu + ((u >> 16) & 1u);
  return (unsigned short)(u >> 16);
}
__device__ __forceinline__ float bf2f(unsigned short s) {
  return __uint_as_float(((unsigned int)s) << 16);
}

// ---------------------------------------------------------------------------
// K0: pre-pass (one-time weight conversion).
//  Wab/Wbb/Wcb = bf16 of ew1 column-blocks [out][k] (128x128 each)
//  m1h/m1l, m2h/m2l = hi/lo bf16 split of mw1, mw2 (for split-precision MFMA)
//  tvg[ty][o] = ew1[:,384:392] . type_emb[ty]
// ---------------------------------------------------------------------------
__global__ __launch_bounds__(256) void k_prep(
    const float* __restrict__ ew1, const float* __restrict__ type_emb,
    const float* __restrict__ mw1, const float* __restrict__ mw2,
    unsigned short* __restrict__ Wab, unsigned short* __restrict__ Wbb,
    unsigned short* __restrict__ Wcb,
    unsigned short* __restrict__ m1h, unsigned short* __restrict__ m1l,
    unsigned short* __restrict__ m2h, unsigned short* __restrict__ m2l,
    float* __restrict__ tvg)
{
  int g = blockIdx.x * 256 + threadIdx.x;   // 0..16383
  int o = g >> 7, k = g & 127;
  Wab[g] = f2bf(ew1[o * IND + k]);
  Wbb[g] = f2bf(ew1[o * IND + 128 + k]);
  Wcb[g] = f2bf(ew1[o * IND + 256 + k]);
  float w1 = mw1[g];
  unsigned short h1 = f2bf(w1);
  m1h[g] = h1; m1l[g] = f2bf(w1 - bf2f(h1));
  float w2 = mw2[g];
  unsigned short h2 = f2bf(w2);
  m2h[g] = h2; m2l[g] = f2bf(w2 - bf2f(h2));
  if (blockIdx.x == 0) {
    int t = threadIdx.x, oo = t & 127, ty = t >> 7;
    float s = 0.f;
#pragma unroll
    for (int j = 0; j < 8; ++j) s += ew1[oo * IND + 384 + j] * type_emb[ty * 8 + j];
    tvg[ty * 128 + oo] = s;
  }
}

// ---------------------------------------------------------------------------
// MFMA micro-GEMM: acc[nt] += X-tile(rows me..me+15) . W^T  (K=128)
// TERMS=2: (Xh+Xl).Wh        (plain weights, split activations)
// TERMS=3: Xh.Wh + Xl.Wh + Xh.Wl   (split both -> ~f32-class product error)
// Fragment layout (verified in k_edge): A row = lane&15, k = (lane>>4)*8+i;
// C/D col = lane&15, row = (lane>>4)*4 + reg.
// ---------------------------------------------------------------------------
template <int TERMS>
__device__ __forceinline__ void mm_acc(
    const unsigned short (*Xh)[136], const unsigned short (*Xl)[136],
    const unsigned short (*Wh)[136], const unsigned short (*Wl)[136],
    int me, int r, int q, f32x4 acc[8])
{
#pragma unroll
  for (int ks = 0; ks < 4; ++ks) {
    bf16x8 ah = *reinterpret_cast<const bf16x8*>(&Xh[me + r][ks * 32 + q * 8]);
    bf16x8 al = *reinterpret_cast<const bf16x8*>(&Xl[me + r][ks * 32 + q * 8]);
#pragma unroll
    for (int nt = 0; nt < 8; ++nt) {
      bf16x8 bh = *reinterpret_cast<const bf16x8*>(&Wh[nt * 16 + r][ks * 32 + q * 8]);
      acc[nt] = __builtin_amdgcn_mfma_f32_16x16x32_bf16(ah, bh, acc[nt], 0, 0, 0);
      acc[nt] = __builtin_amdgcn_mfma_f32_16x16x32_bf16(al, bh, acc[nt], 0, 0, 0);
      if (TERMS == 3) {
        bf16x8 bl = *reinterpret_cast<const bf16x8*>(&Wl[nt * 16 + r][ks * 32 + q * 8]);
        acc[nt] = __builtin_amdgcn_mfma_f32_16x16x32_bf16(ah, bl, acc[nt], 0, 0, 0);
      }
    }
  }
}

// ---------------------------------------------------------------------------
// K1: per-node precompute via MFMA. 128 nodes/block, 8 waves.
//   A = z.Wa^T, B = z.Wb^T          (split-z x bf16-W : alpha-path accuracy)
//   M = mw2.relu(mw1.z + mb1) + mb2 (split-z x split-W : f32-class accuracy)
// LDS: Xh,Xl (z hi/lo, later reused for h1 hi/lo) + Wh,Wl = 139 KB -> 1 blk/CU.
// ---------------------------------------------------------------------------
__global__ __launch_bounds__(512, 1) void k_node_mfma(
    const float* __restrict__ z,
    const unsigned short* __restrict__ Wab, const unsigned short* __restrict__ Wbb,
    const unsigned short* __restrict__ m1h, const unsigned short* __restrict__ m1l,
    const unsigned short* __restrict__ m2h, const unsigned short* __restrict__ m2l,
    const float* __restrict__ mb1, const float* __restrict__ mb2,
    float* __restrict__ A, float* __restrict__ B, unsigned short* __restrict__ Mb)
{
  __shared__ unsigned short Xh[128][136], Xl[128][136];
  __shared__ unsigned short Wh[128][136], Wl[128][136];
  const int t  = threadIdx.x;
  const int n0 = blockIdx.x * 128;

  // stage z, split hi/lo (coalesced; rows past NN clamped, stores guarded)
#pragma unroll
  for (int it = 0; it < 8; ++it) {
    int f = it * 512 + t, rr = f >> 5, c4 = (f & 31) * 4;
    int n = n0 + rr; if (n >= NN) n = NN - 1;
    float4 v = ld4(&z[(size_t)n * D + c4]);
    ushort4 hi, lo;
    hi.x = f2bf(v.x); lo.x = f2bf(v.x - bf2f(hi.x));
    hi.y = f2bf(v.y); lo.y = f2bf(v.y - bf2f(hi.y));
    hi.z = f2bf(v.z); lo.z = f2bf(v.z - bf2f(hi.z));
    hi.w = f2bf(v.w); lo.w = f2bf(v.w - bf2f(hi.w));
    *reinterpret_cast<ushort4*>(&Xh[rr][c4]) = hi;
    *reinterpret_cast<ushort4*>(&Xl[rr][c4]) = lo;
  }
  // stage Wa -> Wh
#pragma unroll
  for (int it = 0; it < 4; ++it) {
    int f = it * 512 + t, row = f >> 4, c8 = (f & 15) * 8;
    *reinterpret_cast<bf16x8*>(&Wh[row][c8]) =
        *reinterpret_cast<const bf16x8*>(&Wab[row * 128 + c8]);
  }
  __syncthreads();

  const int l = t & 63, q = l >> 4, r = l & 15;
  const int me = (t >> 6) * 16;   // wave's 16-node row tile

  f32x4 acc[8];

  // ---- A ----
#pragma unroll
  for (int nt = 0; nt < 8; ++nt) acc[nt] = (f32x4){0.f, 0.f, 0.f, 0.f};
  mm_acc<2>(Xh, Xl, Wh, Wl, me, r, q, acc);
#pragma unroll
  for (int nt = 0; nt < 8; ++nt)
#pragma unroll
    for (int i = 0; i < 4; ++i) {
      int n = n0 + me + q * 4 + i;
      if (n < NN) A[(size_t)n * D + nt * 16 + r] = acc[nt][i];
    }
  __syncthreads();

  // ---- B ----
#pragma unroll
  for (int it = 0; it < 4; ++it) {
    int f = it * 512 + t, row = f >> 4, c8 = (f & 15) * 8;
    *reinterpret_cast<bf16x8*>(&Wh[row][c8]) =
        *reinterpret_cast<const bf16x8*>(&Wbb[row * 128 + c8]);
  }
  __syncthreads();
#pragma unroll
  for (int nt = 0; nt < 8; ++nt) acc[nt] = (f32x4){0.f, 0.f, 0.f, 0.f};
  mm_acc<2>(Xh, Xl, Wh, Wl, me, r, q, acc);
#pragma unroll
  for (int nt = 0; nt < 8; ++nt)
#pragma unroll
    for (int i = 0; i < 4; ++i) {
      int n = n0 + me + q * 4 + i;
      if (n < NN) B[(size_t)n * D + nt * 16 + r] = acc[nt][i];
    }
  __syncthreads();

  // ---- M layer 1: h1 = relu(mw1.z + mb1), split back into Xh/Xl ----
#pragma unroll
  for (int it = 0; it < 4; ++it) {
    int f = it * 512 + t, row = f >> 4, c8 = (f & 15) * 8;
    *reinterpret_cast<bf16x8*>(&Wh[row][c8]) =
        *reinterpret_cast<const bf16x8*>(&m1h[row * 128 + c8]);
    *reinterpret_cast<bf16x8*>(&Wl[row][c8]) =
        *reinterpret_cast<const bf16x8*>(&m1l[row * 128 + c8]);
  }
  __syncthreads();
#pragma unroll
  for (int nt = 0; nt < 8; ++nt) acc[nt] = (f32x4){0.f, 0.f, 0.f, 0.f};
  mm_acc<3>(Xh, Xl, Wh, Wl, me, r, q, acc);
  // write h1 (this wave's own 16 rows only -> wave-local, no cross-wave hazard)
#pragma unroll
  for (int nt = 0; nt < 8; ++nt) {
    int col = nt * 16 + r;
    float b1 = mb1[col];
#pragma unroll
    for (int i = 0; i < 4; ++i) {
      float h = fmaxf(acc[nt][i] + b1, 0.0f);
      unsigned short hh = f2bf(h);
      Xh[me + q * 4 + i][col] = hh;
      Xl[me + q * 4 + i][col] = f2bf(h - bf2f(hh));
    }
  }
  __syncthreads();

  // ---- M layer 2: M = h1.mw2^T + mb2, stored bf16 ----
#pragma unroll
  for (int it = 0; it < 4; ++it) {
    int f = it * 512 + t, row = f >> 4, c8 = (f & 15) * 8;
    *reinterpret_cast<bf16x8*>(&Wh[row][c8]) =
        *reinterpret_cast<const bf16x8*>(&m2h[row * 128 + c8]);
    *reinterpret_cast<bf16x8*>(&Wl[row][c8]) =
        *reinterpret_cast<const bf16x8*>(&m2l[row * 128 + c8]);
  }
  __syncthreads();
#pragma unroll
  for (int nt = 0; nt < 8; ++nt) acc[nt] = (f32x4){0.f, 0.f, 0.f, 0.f};
  mm_acc<3>(Xh, Xl, Wh, Wl, me, r, q, acc);
#pragma unroll
  for (int nt = 0; nt < 8; ++nt) {
    int col = nt * 16 + r;
    float b2 = mb2[col];
#pragma unroll
    for (int i = 0; i < 4; ++i) {
      int n = n0 + me + q * 4 + i;
      if (n < NN) Mb[(size_t)n * D + col] = f2bf(acc[nt][i] + b2);
    }
  }
}

// ---------------------------------------------------------------------------
// CSR build: histogram -> single-block scan -> fill (stores eid + dst)
// ---------------------------------------------------------------------------
__global__ __launch_bounds__(256) void k_hist(const int* __restrict__ ei,
                                              int* __restrict__ deg)
{
  int e = blockIdx.x * 256 + threadIdx.x;
  if (e < NE) atomicAdd(&deg[ei[e]], 1);
}

__global__ __launch_bounds__(1024) void k_scan(const int* __restrict__ deg,
                                               int* __restrict__ rowptr,
                                               int* __restrict__ cursor)
{
  __shared__ int ps[1024];
  const int t = threadIdx.x;
  const int CH = 49;
  int lo = t * CH, hi = min(lo + CH, NN);
  if (lo > NN) { lo = NN; hi = NN; }
  int s = 0;
  for (int i = lo; i < hi; ++i) s += deg[i];
  ps[t] = s;
  __syncthreads();
  for (int off = 1; off < 1024; off <<= 1) {
    int v = (t >= off) ? ps[t - off] : 0;
    __syncthreads();
    ps[t] += v;
    __syncthreads();
  }
  int run = t ? ps[t - 1] : 0;
  for (int i = lo; i < hi; ++i) {
    rowptr[i] = run;
    cursor[i] = run;
    run += deg[i];
  }
  if (t == 1023) rowptr[NN] = NE;
}

__global__ __launch_bounds__(256) void k_fill(const int* __restrict__ ei,
                                              int* __restrict__ cursor,
                                              int* __restrict__ eid,
                                              int* __restrict__ de_perm)
{
  int e = blockIdx.x * 256 + threadIdx.x;
  if (e < NE) {
    int pos = atomicAdd(&cursor[ei[e]], 1);
    eid[pos] = e;
    de_perm[pos] = ei[NE + e];
  }
}

// ---------------------------------------------------------------------------
// K2: per-edge pass, bf16 MFMA. 128 edges/block, 8 waves, CSR order.
// (unchanged from round 5 - verified)
// ---------------------------------------------------------------------------
__global__ __launch_bounds__(512, 4) void k_edge_mfma(
    const float* __restrict__ z, const int* __restrict__ ei,
    const int* __restrict__ etype,
    const unsigned short* __restrict__ Wcb, const float* __restrict__ tvg,
    const float* __restrict__ eb1, const float* __restrict__ ew2,
    const float* __restrict__ eb2,
    const float* __restrict__ A, const float* __restrict__ B,
    const int* __restrict__ eid, const int* __restrict__ de_perm,
    float* __restrict__ wexp_perm)
{
  __shared__ unsigned short Xb[128][136];
  __shared__ unsigned short Wb[128][136];
  __shared__ int se[128], de[128], tye[128];

  const int t  = threadIdx.x;
  const int e0 = blockIdx.x * 128;

  if (t < 128) {
    int pos = e0 + t;
    if (pos < NE) {
      int e  = eid[pos];
      se[t]  = ei[e];
      de[t]  = de_perm[pos];
      tye[t] = etype[e];
    } else { se[t] = 0; de[t] = 0; tye[t] = 0; }
  }
#pragma unroll
  for (int it = 0; it < 4; ++it) {
    int f = it * 512 + t, row = f >> 4, c8 = (f & 15) * 8;
    *reinterpret_cast<bf16x8*>(&Wb[row][c8]) =
        *reinterpret_cast<const bf16x8*>(&Wcb[row * 128 + c8]);
  }
  __syncthreads();

#pragma unroll
  for (int it = 0; it < 8; ++it) {
    int f = it * 512 + t, r = f >> 5, c4 = (f & 31) * 4;
    float4 a = ld4(&z[(size_t)se[r] * D + c4]);
    float4 b = ld4(&z[(size_t)de[r] * D + c4]);
    ushort4 v;
    v.x = f2bf(fabsf(a.x - b.x)); v.y = f2bf(fabsf(a.y - b.y));
    v.z = f2bf(fabsf(a.z - b.z)); v.w = f2bf(fabsf(a.w - b.w));
    *reinterpret_cast<ushort4*>(&Xb[r][c4]) = v;
  }
  __syncthreads();

  const int l = t & 63, q = l >> 4, r = l & 15;
  const int me = (t >> 6) * 16;

  f32x4 acc[8];
#pragma unroll
  for (int nt = 0; nt < 8; ++nt) acc[nt] = (f32x4){0.f, 0.f, 0.f, 0.f};

#pragma unroll
  for (int ks = 0; ks < 4; ++ks) {
    bf16x8 a = *reinterpret_cast<const bf16x8*>(&Xb[me + r][ks * 32 + q * 8]);
#pragma unroll
    for (int nt = 0; nt < 8; ++nt) {
      bf16x8 b = *reinterpret_cast<const bf16x8*>(&Wb[nt * 16 + r][ks * 32 + q * 8]);
      acc[nt] = __builtin_amdgcn_mfma_f32_16x16x32_bf16(a, b, acc[nt], 0, 0, 0);
    }
  }

  int s[4], dd[4], ty[4];
#pragma unroll
  for (int i = 0; i < 4; ++i) {
    int el = me + q * 4 + i;
    s[i] = se[el]; dd[i] = de[el]; ty[i] = tye[el];
  }
  float p[4] = {0.f, 0.f, 0.f, 0.f};
#pragma unroll
  for (int nt = 0; nt < 8; ++nt) {
    int col = nt * 16 + r;
    float e1  = eb1[col], w2 = ew2[col];
    float tva = tvg[col], tvb = tvg[128 + col];
#pragma unroll
    for (int i = 0; i < 4; ++i) {
      float h = acc[nt][i] + A[(size_t)s[i] * D + col] + B[(size_t)dd[i] * D + col]
              + (ty[i] ? tvb : tva) + e1;
      p[i] += fmaxf(h, 0.f) * w2;
    }
  }
#pragma unroll
  for (int m = 1; m < 16; m <<= 1) {
#pragma unroll
    for (int i = 0; i < 4; ++i) p[i] += __shfl_xor(p[i], m);
  }
  if (r == 0) {
    float b2 = eb2[0];
#pragma unroll
    for (int i = 0; i < 4; ++i) {
      int pos = e0 + me + q * 4 + i;
      if (pos < NE) {
        float w = 1.0f / (1.0f + expf(-(p[i] + b2)));  // sigmoid
        wexp_perm[pos] = expf(w);                      // w in (0,1): stable
      }
    }
  }
}

// ---------------------------------------------------------------------------
// K3: fused per-node aggregation + residual + LayerNorm (unchanged).
// ---------------------------------------------------------------------------
__global__ __launch_bounds__(256) void k_agg(
    const float* __restrict__ z, const float* __restrict__ wexp_perm,
    const unsigned short* __restrict__ Mb, const int* __restrict__ rowptr,
    const int* __restrict__ eid, const int* __restrict__ de_perm,
    const float* __restrict__ gamma, const float* __restrict__ beta,
    float* __restrict__ out, float* __restrict__ alpha_out)
{
  const int t = threadIdx.x;
  const int n = blockIdx.x * 4 + (t >> 6);
  const int l = t & 63;
  const int start = rowptr[n], end = rowptr[n + 1];

  float tot = 0.f;
  for (int base = start; base < end; base += 64) {
    if (base + l < end) tot += wexp_perm[base + l];
  }
#pragma unroll
  for (int off = 32; off; off >>= 1) tot += __shfl_xor(tot, off);
  const float inv = 1.0f / (tot + 1e-12f);

  float2 acc = make_float2(0.f, 0.f);
  for (int base = start; base < end; base += 64) {
    int cnt = min(64, end - base);
    int dd = 0;
    float al = 0.f;
    if (l < cnt) {
      int pos = base + l;
      al = wexp_perm[pos] * inv;
      dd = de_perm[pos];
      alpha_out[eid[pos]] = al;
    }
    for (int i = 0; i < cnt; ++i) {
      float a = __shfl(al, i);
      int   d = __shfl(dd, i);
      ushort2 m = *reinterpret_cast<const ushort2*>(&Mb[(size_t)d * D + l * 2]);
      acc.x = fmaf(a, bf2f(m.x), acc.x);
      acc.y = fmaf(a, bf2f(m.y), acc.y);
    }
  }

  float2 xz = *reinterpret_cast<const float2*>(&z[(size_t)n * D + l * 2]);
  float x0 = xz.x + acc.x, x1 = xz.y + acc.y;
  float s = x0 + x1;
#pragma unroll
  for (int off = 32; off; off >>= 1) s += __shfl_xor(s, off);
  const float mu = s * (1.0f / 128.0f);
  float d0 = x0 - mu, d1 = x1 - mu;
  float q = d0 * d0 + d1 * d1;
#pragma unroll
  for (int off = 32; off; off >>= 1) q += __shfl_xor(q, off);
  const float rstd = rsqrtf(q * (1.0f / 128.0f) + 1e-5f);
  float2 g = *reinterpret_cast<const float2*>(&gamma[l * 2]);
  float2 b = *reinterpret_cast<const float2*>(&beta[l * 2]);
  float2 o = make_float2(d0 * rstd * g.x + b.x, d1 * rstd * g.y + b.y);
  *reinterpret_cast<float2*>(&out[(size_t)n * D + l * 2]) = o;
}

// ---------------------------------------------------------------------------
extern "C" void kernel_launch(void* const* d_in, const int* in_sizes, int n_in,
                              void* d_out, int out_size, void* d_ws, size_t ws_size,
                              hipStream_t stream)
{
  const float* z        = (const float*)d_in[0];
  const int*   ei       = (const int*)d_in[1];   // [2,E]: src row, then dst row
  const int*   etype    = (const int*)d_in[2];
  const float* type_emb = (const float*)d_in[3];
  const float* ew1      = (const float*)d_in[4];
  const float* eb1      = (const float*)d_in[5];
  const float* ew2      = (const float*)d_in[6];
  const float* eb2      = (const float*)d_in[7];
  const float* mw1      = (const float*)d_in[8];
  const float* mb1      = (const float*)d_in[9];
  const float* mw2      = (const float*)d_in[10];
  const float* mb2      = (const float*)d_in[11];
  const float* gamma    = (const float*)d_in[12];
  const float* beta     = (const float*)d_in[13];

  // workspace: A | B (f32) | Mb (bf16) | wexp_perm || ints || bf16 weights | tvg
  float*          ws        = (float*)d_ws;
  float*          A         = ws;
  float*          B         = ws + 6400000;
  unsigned short* Mb        = (unsigned short*)(ws + 12800000);
  float*          wexp_perm = ws + 16000000;
  int*            deg       = (int*)(ws + 16600000);
  int*            rowptr    = deg + 50000;
  int*            cursor    = rowptr + 50004;
  int*            eid       = cursor + 50000;
  int*            de_perm   = eid + 600000;
  unsigned short* Wcb       = (unsigned short*)(ws + 18000000);
  float*          tvg       = ws + 18100000;
  unsigned short* Wab       = (unsigned short*)(ws + 18200000);
  unsigned short* Wbb       = (unsigned short*)(ws + 18210000);
  unsigned short* m1h       = (unsigned short*)(ws + 18220000);
  unsigned short* m1l       = (unsigned short*)(ws + 18230000);
  unsigned short* m2h       = (unsigned short*)(ws + 18240000);
  unsigned short* m2l       = (unsigned short*)(ws + 18250000);

  float* out       = (float*)d_out;
  float* alpha_out = out + (size_t)NN * D;

  hipMemsetAsync(deg, 0, 50000 * sizeof(int), stream);

  k_prep<<<64, 256, 0, stream>>>(ew1, type_emb, mw1, mw2,
                                 Wab, Wbb, Wcb, m1h, m1l, m2h, m2l, tvg);
  k_hist<<<(NE + 255) / 256, 256, 0, stream>>>(ei, deg);
  k_scan<<<1, 1024, 0, stream>>>(deg, rowptr, cursor);
  k_fill<<<(NE + 255) / 256, 256, 0, stream>>>(ei, cursor, eid, de_perm);
  k_node_mfma<<<(NN + 127) / 128, 512, 0, stream>>>(z, Wab, Wbb, m1h, m1l,
                                                    m2h, m2l, mb1, mb2, A, B, Mb);
  k_edge_mfma<<<(NE + 127) / 128, 512, 0, stream>>>(z, ei, etype, Wcb, tvg,
                                                    eb1, ew2, eb2, A, B,
                                                    eid, de_perm, wexp_perm);
  k_agg<<<NN / 4, 256, 0, stream>>>(z, wexp_perm, Mb, rowptr, eid, de_perm,
                                    gamma, beta, out, alpha_out);
}

// Round 8
// 374.208 us; speedup vs baseline: 8.4221x; 1.0390x over previous
//
#include <hip/hip_runtime.h>
#include <math.h>

// Problem constants (fixed by the reference)
constexpr int NN  = 50000;   // nodes
constexpr int NE  = 600000;  // edges
constexpr int D   = 128;     // DIM == HID
constexpr int IND = 392;     // 3*DIM + TEMB

typedef __attribute__((ext_vector_type(8))) short bf16x8;   // 8 bf16 = 4 VGPR
typedef __attribute__((ext_vector_type(4))) float f32x4;    // MFMA accumulator

__device__ __forceinline__ float4 ld4(const float* p) { return *reinterpret_cast<const float4*>(p); }

// float -> bf16 (RNE) and back
__device__ __forceinline__ unsigned short f2bf(float f) {
  unsigned int u = __float_as_uint(f);
  u += 0x7fffu + ((u >> 16) & 1u);
  return (unsigned short)(u >> 16);
}
__device__ __forceinline__ float bf2f(unsigned short s) {
  return __uint_as_float(((unsigned int)s) << 16);
}

// ---------------------------------------------------------------------------
// K0: pre-pass (one-time weight conversion).
// ---------------------------------------------------------------------------
__global__ __launch_bounds__(256) void k_prep(
    const float* __restrict__ ew1, const float* __restrict__ type_emb,
    const float* __restrict__ mw1, const float* __restrict__ mw2,
    unsigned short* __restrict__ Wab, unsigned short* __restrict__ Wbb,
    unsigned short* __restrict__ Wcb,
    unsigned short* __restrict__ m1h, unsigned short* __restrict__ m1l,
    unsigned short* __restrict__ m2h, unsigned short* __restrict__ m2l,
    float* __restrict__ tvg)
{
  int g = blockIdx.x * 256 + threadIdx.x;   // 0..16383
  int o = g >> 7, k = g & 127;
  Wab[g] = f2bf(ew1[o * IND + k]);
  Wbb[g] = f2bf(ew1[o * IND + 128 + k]);
  Wcb[g] = f2bf(ew1[o * IND + 256 + k]);
  float w1 = mw1[g];
  unsigned short h1 = f2bf(w1);
  m1h[g] = h1; m1l[g] = f2bf(w1 - bf2f(h1));
  float w2 = mw2[g];
  unsigned short h2 = f2bf(w2);
  m2h[g] = h2; m2l[g] = f2bf(w2 - bf2f(h2));
  if (blockIdx.x == 0) {
    int t = threadIdx.x, oo = t & 127, ty = t >> 7;
    float s = 0.f;
#pragma unroll
    for (int j = 0; j < 8; ++j) s += ew1[oo * IND + 384 + j] * type_emb[ty * 8 + j];
    tvg[ty * 128 + oo] = s;
  }
}

// ---------------------------------------------------------------------------
// MFMA micro-GEMM: acc[nt] += X-tile(rows me..me+15) . W^T  (K=128)
// TERMS=2: (Xh+Xl).Wh ; TERMS=3: Xh.Wh + Xl.Wh + Xh.Wl (f32-class)
// ---------------------------------------------------------------------------
template <int TERMS>
__device__ __forceinline__ void mm_acc(
    const unsigned short (*Xh)[136], const unsigned short (*Xl)[136],
    const unsigned short (*Wh)[136], const unsigned short (*Wl)[136],
    int me, int r, int q, f32x4 acc[8])
{
#pragma unroll
  for (int ks = 0; ks < 4; ++ks) {
    bf16x8 ah = *reinterpret_cast<const bf16x8*>(&Xh[me + r][ks * 32 + q * 8]);
    bf16x8 al = *reinterpret_cast<const bf16x8*>(&Xl[me + r][ks * 32 + q * 8]);
#pragma unroll
    for (int nt = 0; nt < 8; ++nt) {
      bf16x8 bh = *reinterpret_cast<const bf16x8*>(&Wh[nt * 16 + r][ks * 32 + q * 8]);
      acc[nt] = __builtin_amdgcn_mfma_f32_16x16x32_bf16(ah, bh, acc[nt], 0, 0, 0);
      acc[nt] = __builtin_amdgcn_mfma_f32_16x16x32_bf16(al, bh, acc[nt], 0, 0, 0);
      if (TERMS == 3) {
        bf16x8 bl = *reinterpret_cast<const bf16x8*>(&Wl[nt * 16 + r][ks * 32 + q * 8]);
        acc[nt] = __builtin_amdgcn_mfma_f32_16x16x32_bf16(ah, bl, acc[nt], 0, 0, 0);
      }
    }
  }
}

// ---------------------------------------------------------------------------
// K1: per-node precompute via MFMA. 128 nodes/block, 8 waves.
//   Ab = bf16(z.Wa^T), Bb = bf16(z.Wb^T), Mb = bf16(M), zb = bf16(z)
// ---------------------------------------------------------------------------
__global__ __launch_bounds__(512, 1) void k_node_mfma(
    const float* __restrict__ z,
    const unsigned short* __restrict__ Wab, const unsigned short* __restrict__ Wbb,
    const unsigned short* __restrict__ m1h, const unsigned short* __restrict__ m1l,
    const unsigned short* __restrict__ m2h, const unsigned short* __restrict__ m2l,
    const float* __restrict__ mb1, const float* __restrict__ mb2,
    unsigned short* __restrict__ Ab, unsigned short* __restrict__ Bb,
    unsigned short* __restrict__ Mb, unsigned short* __restrict__ zb)
{
  __shared__ unsigned short Xh[128][136], Xl[128][136];
  __shared__ unsigned short Wh[128][136], Wl[136][136];
  const int t  = threadIdx.x;
  const int n0 = blockIdx.x * 128;

  // stage z, split hi/lo; also write zb = bf16(z)
#pragma unroll
  for (int it = 0; it < 8; ++it) {
    int f = it * 512 + t, rr = f >> 5, c4 = (f & 31) * 4;
    int n = n0 + rr; if (n >= NN) n = NN - 1;
    float4 v = ld4(&z[(size_t)n * D + c4]);
    ushort4 hi, lo;
    hi.x = f2bf(v.x); lo.x = f2bf(v.x - bf2f(hi.x));
    hi.y = f2bf(v.y); lo.y = f2bf(v.y - bf2f(hi.y));
    hi.z = f2bf(v.z); lo.z = f2bf(v.z - bf2f(hi.z));
    hi.w = f2bf(v.w); lo.w = f2bf(v.w - bf2f(hi.w));
    *reinterpret_cast<ushort4*>(&Xh[rr][c4]) = hi;
    *reinterpret_cast<ushort4*>(&Xl[rr][c4]) = lo;
    if (n0 + rr < NN)
      *reinterpret_cast<ushort4*>(&zb[(size_t)(n0 + rr) * D + c4]) = hi;
  }
#pragma unroll
  for (int it = 0; it < 4; ++it) {
    int f = it * 512 + t, row = f >> 4, c8 = (f & 15) * 8;
    *reinterpret_cast<bf16x8*>(&Wh[row][c8]) =
        *reinterpret_cast<const bf16x8*>(&Wab[row * 128 + c8]);
  }
  __syncthreads();

  const int l = t & 63, q = l >> 4, r = l & 15;
  const int me = (t >> 6) * 16;

  f32x4 acc[8];

  // ---- A ----
#pragma unroll
  for (int nt = 0; nt < 8; ++nt) acc[nt] = (f32x4){0.f, 0.f, 0.f, 0.f};
  mm_acc<2>(Xh, Xl, Wh, Wl, me, r, q, acc);
#pragma unroll
  for (int nt = 0; nt < 8; ++nt)
#pragma unroll
    for (int i = 0; i < 4; ++i) {
      int n = n0 + me + q * 4 + i;
      if (n < NN) Ab[(size_t)n * D + nt * 16 + r] = f2bf(acc[nt][i]);
    }
  __syncthreads();

  // ---- B ----
#pragma unroll
  for (int it = 0; it < 4; ++it) {
    int f = it * 512 + t, row = f >> 4, c8 = (f & 15) * 8;
    *reinterpret_cast<bf16x8*>(&Wh[row][c8]) =
        *reinterpret_cast<const bf16x8*>(&Wbb[row * 128 + c8]);
  }
  __syncthreads();
#pragma unroll
  for (int nt = 0; nt < 8; ++nt) acc[nt] = (f32x4){0.f, 0.f, 0.f, 0.f};
  mm_acc<2>(Xh, Xl, Wh, Wl, me, r, q, acc);
#pragma unroll
  for (int nt = 0; nt < 8; ++nt)
#pragma unroll
    for (int i = 0; i < 4; ++i) {
      int n = n0 + me + q * 4 + i;
      if (n < NN) Bb[(size_t)n * D + nt * 16 + r] = f2bf(acc[nt][i]);
    }
  __syncthreads();

  // ---- M layer 1: h1 = relu(mw1.z + mb1), split back into Xh/Xl ----
#pragma unroll
  for (int it = 0; it < 4; ++it) {
    int f = it * 512 + t, row = f >> 4, c8 = (f & 15) * 8;
    *reinterpret_cast<bf16x8*>(&Wh[row][c8]) =
        *reinterpret_cast<const bf16x8*>(&m1h[row * 128 + c8]);
    *reinterpret_cast<bf16x8*>(&Wl[row][c8]) =
        *reinterpret_cast<const bf16x8*>(&m1l[row * 128 + c8]);
  }
  __syncthreads();
#pragma unroll
  for (int nt = 0; nt < 8; ++nt) acc[nt] = (f32x4){0.f, 0.f, 0.f, 0.f};
  mm_acc<3>(Xh, Xl, Wh, Wl, me, r, q, acc);
#pragma unroll
  for (int nt = 0; nt < 8; ++nt) {
    int col = nt * 16 + r;
    float b1 = mb1[col];
#pragma unroll
    for (int i = 0; i < 4; ++i) {
      float h = fmaxf(acc[nt][i] + b1, 0.0f);
      unsigned short hh = f2bf(h);
      Xh[me + q * 4 + i][col] = hh;
      Xl[me + q * 4 + i][col] = f2bf(h - bf2f(hh));
    }
  }
  __syncthreads();

  // ---- M layer 2: M = h1.mw2^T + mb2, stored bf16 ----
#pragma unroll
  for (int it = 0; it < 4; ++it) {
    int f = it * 512 + t, row = f >> 4, c8 = (f & 15) * 8;
    *reinterpret_cast<bf16x8*>(&Wh[row][c8]) =
        *reinterpret_cast<const bf16x8*>(&m2h[row * 128 + c8]);
    *reinterpret_cast<bf16x8*>(&Wl[row][c8]) =
        *reinterpret_cast<const bf16x8*>(&m2l[row * 128 + c8]);
  }
  __syncthreads();
#pragma unroll
  for (int nt = 0; nt < 8; ++nt) acc[nt] = (f32x4){0.f, 0.f, 0.f, 0.f};
  mm_acc<3>(Xh, Xl, Wh, Wl, me, r, q, acc);
#pragma unroll
  for (int nt = 0; nt < 8; ++nt) {
    int col = nt * 16 + r;
    float b2 = mb2[col];
#pragma unroll
    for (int i = 0; i < 4; ++i) {
      int n = n0 + me + q * 4 + i;
      if (n < NN) Mb[(size_t)n * D + col] = f2bf(acc[nt][i] + b2);
    }
  }
}

// ---------------------------------------------------------------------------
// CSR build: histogram -> single-block scan -> fill (stores eid + dst)
// ---------------------------------------------------------------------------
__global__ __launch_bounds__(256) void k_hist(const int* __restrict__ ei,
                                              int* __restrict__ deg)
{
  int e = blockIdx.x * 256 + threadIdx.x;
  if (e < NE) atomicAdd(&deg[ei[e]], 1);
}

__global__ __launch_bounds__(1024) void k_scan(const int* __restrict__ deg,
                                               int* __restrict__ rowptr,
                                               int* __restrict__ cursor)
{
  __shared__ int ps[1024];
  const int t = threadIdx.x;
  const int CH = 49;
  int lo = t * CH, hi = min(lo + CH, NN);
  if (lo > NN) { lo = NN; hi = NN; }
  int s = 0;
  for (int i = lo; i < hi; ++i) s += deg[i];
  ps[t] = s;
  __syncthreads();
  for (int off = 1; off < 1024; off <<= 1) {
    int v = (t >= off) ? ps[t - off] : 0;
    __syncthreads();
    ps[t] += v;
    __syncthreads();
  }
  int run = t ? ps[t - 1] : 0;
  for (int i = lo; i < hi; ++i) {
    rowptr[i] = run;
    cursor[i] = run;
    run += deg[i];
  }
  if (t == 1023) rowptr[NN] = NE;
}

__global__ __launch_bounds__(256) void k_fill(const int* __restrict__ ei,
                                              int* __restrict__ cursor,
                                              int* __restrict__ eid,
                                              int* __restrict__ de_perm)
{
  int e = blockIdx.x * 256 + threadIdx.x;
  if (e < NE) {
    int pos = atomicAdd(&cursor[ei[e]], 1);
    eid[pos] = e;
    de_perm[pos] = ei[NE + e];
  }
}

// ---------------------------------------------------------------------------
// K2: per-edge pass, bf16 MFMA, bf16 gathers. 128 edges/block, 8 waves, CSR
// order with XCD-aware block swizzle (consecutive CSR blocks share src rows
// -> keep them on one XCD's L2).
// ---------------------------------------------------------------------------
__global__ __launch_bounds__(512, 4) void k_edge_mfma(
    const unsigned short* __restrict__ zb, const int* __restrict__ ei,
    const int* __restrict__ etype,
    const unsigned short* __restrict__ Wcb, const float* __restrict__ tvg,
    const float* __restrict__ eb1, const float* __restrict__ ew2,
    const float* __restrict__ eb2,
    const unsigned short* __restrict__ Ab, const unsigned short* __restrict__ Bb,
    const int* __restrict__ eid, const int* __restrict__ de_perm,
    float* __restrict__ wexp_perm)
{
  __shared__ unsigned short Xb[128][136];
  __shared__ unsigned short Wb[128][136];
  __shared__ int se[128], de[128], tye[128];

  const int t = threadIdx.x;
  // XCD swizzle (grid 4688 % 8 == 0 -> simple bijective form)
  const int nx  = gridDim.x >> 3;
  const int swz = (blockIdx.x & 7) * nx + (blockIdx.x >> 3);
  const int e0  = swz * 128;

  if (t < 128) {
    int pos = e0 + t;
    if (pos < NE) {
      int e  = eid[pos];
      se[t]  = ei[e];
      de[t]  = de_perm[pos];
      tye[t] = etype[e];
    } else { se[t] = 0; de[t] = 0; tye[t] = 0; }
  }
#pragma unroll
  for (int it = 0; it < 4; ++it) {
    int f = it * 512 + t, row = f >> 4, c8 = (f & 15) * 8;
    *reinterpret_cast<bf16x8*>(&Wb[row][c8]) =
        *reinterpret_cast<const bf16x8*>(&Wcb[row * 128 + c8]);
  }
  __syncthreads();

  // stage |zb[src]-zb[dst]| (bf16 gathers: 256B/row)
#pragma unroll
  for (int it = 0; it < 8; ++it) {
    int f = it * 512 + t, r = f >> 5, c4 = (f & 31) * 4;
    ushort4 a = *reinterpret_cast<const ushort4*>(&zb[(size_t)se[r] * D + c4]);
    ushort4 b = *reinterpret_cast<const ushort4*>(&zb[(size_t)de[r] * D + c4]);
    ushort4 v;
    v.x = f2bf(fabsf(bf2f(a.x) - bf2f(b.x)));
    v.y = f2bf(fabsf(bf2f(a.y) - bf2f(b.y)));
    v.z = f2bf(fabsf(bf2f(a.z) - bf2f(b.z)));
    v.w = f2bf(fabsf(bf2f(a.w) - bf2f(b.w)));
    *reinterpret_cast<ushort4*>(&Xb[r][c4]) = v;
  }
  __syncthreads();

  const int l = t & 63, q = l >> 4, r = l & 15;
  const int me = (t >> 6) * 16;

  f32x4 acc[8];
#pragma unroll
  for (int nt = 0; nt < 8; ++nt) acc[nt] = (f32x4){0.f, 0.f, 0.f, 0.f};

#pragma unroll
  for (int ks = 0; ks < 4; ++ks) {
    bf16x8 a = *reinterpret_cast<const bf16x8*>(&Xb[me + r][ks * 32 + q * 8]);
#pragma unroll
    for (int nt = 0; nt < 8; ++nt) {
      bf16x8 b = *reinterpret_cast<const bf16x8*>(&Wb[nt * 16 + r][ks * 32 + q * 8]);
      acc[nt] = __builtin_amdgcn_mfma_f32_16x16x32_bf16(a, b, acc[nt], 0, 0, 0);
    }
  }

  int s[4], dd[4], ty[4];
#pragma unroll
  for (int i = 0; i < 4; ++i) {
    int el = me + q * 4 + i;
    s[i] = se[el]; dd[i] = de[el]; ty[i] = tye[el];
  }
  float p[4] = {0.f, 0.f, 0.f, 0.f};
#pragma unroll
  for (int nt = 0; nt < 8; ++nt) {
    int col = nt * 16 + r;
    float e1  = eb1[col], w2 = ew2[col];
    float tva = tvg[col], tvb = tvg[128 + col];
#pragma unroll
    for (int i = 0; i < 4; ++i) {
      float h = acc[nt][i] + bf2f(Ab[(size_t)s[i] * D + col])
              + bf2f(Bb[(size_t)dd[i] * D + col]) + (ty[i] ? tvb : tva) + e1;
      p[i] += fmaxf(h, 0.f) * w2;
    }
  }
#pragma unroll
  for (int m = 1; m < 16; m <<= 1) {
#pragma unroll
    for (int i = 0; i < 4; ++i) p[i] += __shfl_xor(p[i], m);
  }
  if (r == 0) {
    float b2 = eb2[0];
#pragma unroll
    for (int i = 0; i < 4; ++i) {
      int pos = e0 + me + q * 4 + i;
      if (pos < NE) {
        float w = 1.0f / (1.0f + expf(-(p[i] + b2)));  // sigmoid
        wexp_perm[pos] = expf(w);                      // w in (0,1): stable
      }
    }
  }
}

// ---------------------------------------------------------------------------
// K3: fused per-node aggregation + residual + LayerNorm (unchanged).
// ---------------------------------------------------------------------------
__global__ __launch_bounds__(256) void k_agg(
    const float* __restrict__ z, const float* __restrict__ wexp_perm,
    const unsigned short* __restrict__ Mb, const int* __restrict__ rowptr,
    const int* __restrict__ eid, const int* __restrict__ de_perm,
    const float* __restrict__ gamma, const float* __restrict__ beta,
    float* __restrict__ out, float* __restrict__ alpha_out)
{
  const int t = threadIdx.x;
  const int n = blockIdx.x * 4 + (t >> 6);
  const int l = t & 63;
  const int start = rowptr[n], end = rowptr[n + 1];

  float tot = 0.f;
  for (int base = start; base < end; base += 64) {
    if (base + l < end) tot += wexp_perm[base + l];
  }
#pragma unroll
  for (int off = 32; off; off >>= 1) tot += __shfl_xor(tot, off);
  const float inv = 1.0f / (tot + 1e-12f);

  float2 acc = make_float2(0.f, 0.f);
  for (int base = start; base < end; base += 64) {
    int cnt = min(64, end - base);
    int dd = 0;
    float al = 0.f;
    if (l < cnt) {
      int pos = base + l;
      al = wexp_perm[pos] * inv;
      dd = de_perm[pos];
      alpha_out[eid[pos]] = al;
    }
    for (int i = 0; i < cnt; ++i) {
      float a = __shfl(al, i);
      int   d = __shfl(dd, i);
      ushort2 m = *reinterpret_cast<const ushort2*>(&Mb[(size_t)d * D + l * 2]);
      acc.x = fmaf(a, bf2f(m.x), acc.x);
      acc.y = fmaf(a, bf2f(m.y), acc.y);
    }
  }

  float2 xz = *reinterpret_cast<const float2*>(&z[(size_t)n * D + l * 2]);
  float x0 = xz.x + acc.x, x1 = xz.y + acc.y;
  float s = x0 + x1;
#pragma unroll
  for (int off = 32; off; off >>= 1) s += __shfl_xor(s, off);
  const float mu = s * (1.0f / 128.0f);
  float d0 = x0 - mu, d1 = x1 - mu;
  float q = d0 * d0 + d1 * d1;
#pragma unroll
  for (int off = 32; off; off >>= 1) q += __shfl_xor(q, off);
  const float rstd = rsqrtf(q * (1.0f / 128.0f) + 1e-5f);
  float2 g = *reinterpret_cast<const float2*>(&gamma[l * 2]);
  float2 b = *reinterpret_cast<const float2*>(&beta[l * 2]);
  float2 o = make_float2(d0 * rstd * g.x + b.x, d1 * rstd * g.y + b.y);
  *reinterpret_cast<float2*>(&out[(size_t)n * D + l * 2]) = o;
}

// ---------------------------------------------------------------------------
extern "C" void kernel_launch(void* const* d_in, const int* in_sizes, int n_in,
                              void* d_out, int out_size, void* d_ws, size_t ws_size,
                              hipStream_t stream)
{
  const float* z        = (const float*)d_in[0];
  const int*   ei       = (const int*)d_in[1];   // [2,E]: src row, then dst row
  const int*   etype    = (const int*)d_in[2];
  const float* type_emb = (const float*)d_in[3];
  const float* ew1      = (const float*)d_in[4];
  const float* eb1      = (const float*)d_in[5];
  const float* ew2      = (const float*)d_in[6];
  const float* eb2      = (const float*)d_in[7];
  const float* mw1      = (const float*)d_in[8];
  const float* mb1      = (const float*)d_in[9];
  const float* mw2      = (const float*)d_in[10];
  const float* mb2      = (const float*)d_in[11];
  const float* gamma    = (const float*)d_in[12];
  const float* beta     = (const float*)d_in[13];

  // workspace (float-unit offsets):
  // Ab|Bb|Mb|zb (bf16, 3.2M floats each) | wexp_perm | ints | bf16 weights | tvg
  float*          ws        = (float*)d_ws;
  unsigned short* Ab        = (unsigned short*)(ws);
  unsigned short* Bb        = (unsigned short*)(ws + 3200000);
  unsigned short* Mb        = (unsigned short*)(ws + 6400000);
  unsigned short* zb        = (unsigned short*)(ws + 9600000);
  float*          wexp_perm = ws + 12800000;
  int*            deg       = (int*)(ws + 13400000);
  int*            rowptr    = deg + 50000;
  int*            cursor    = rowptr + 50004;
  int*            eid       = cursor + 50000;
  int*            de_perm   = eid + 600000;
  unsigned short* Wcb       = (unsigned short*)(ws + 14800000);
  float*          tvg       = ws + 14810000;
  unsigned short* Wab       = (unsigned short*)(ws + 14820000);
  unsigned short* Wbb       = (unsigned short*)(ws + 14830000);
  unsigned short* m1h       = (unsigned short*)(ws + 14840000);
  unsigned short* m1l       = (unsigned short*)(ws + 14850000);
  unsigned short* m2h       = (unsigned short*)(ws + 14860000);
  unsigned short* m2l       = (unsigned short*)(ws + 14870000);

  float* out       = (float*)d_out;
  float* alpha_out = out + (size_t)NN * D;

  hipMemsetAsync(deg, 0, 50000 * sizeof(int), stream);

  k_prep<<<64, 256, 0, stream>>>(ew1, type_emb, mw1, mw2,
                                 Wab, Wbb, Wcb, m1h, m1l, m2h, m2l, tvg);
  k_hist<<<(NE + 255) / 256, 256, 0, stream>>>(ei, deg);
  k_scan<<<1, 1024, 0, stream>>>(deg, rowptr, cursor);
  k_fill<<<(NE + 255) / 256, 256, 0, stream>>>(ei, cursor, eid, de_perm);
  k_node_mfma<<<(NN + 127) / 128, 512, 0, stream>>>(z, Wab, Wbb, m1h, m1l,
                                                    m2h, m2l, mb1, mb2,
                                                    Ab, Bb, Mb, zb);
  k_edge_mfma<<<(NE + 127) / 128, 512, 0, stream>>>(zb, ei, etype, Wcb, tvg,
                                                    eb1, ew2, eb2, Ab, Bb,
                                                    eid, de_perm, wexp_perm);
  k_agg<<<NN / 4, 256, 0, stream>>>(z, wexp_perm, Mb, rowptr, eid, de_perm,
                                    gamma, beta, out, alpha_out);
}

// Round 9
// 272.947 us; speedup vs baseline: 11.5467x; 1.3710x over previous
//
#include <hip/hip_runtime.h>
#include <math.h>

// Problem constants (fixed by the reference)
constexpr int NN  = 50000;   // nodes
constexpr int NE  = 600000;  // edges
constexpr int D   = 128;     // DIM == HID
constexpr int IND = 392;     // 3*DIM + TEMB

typedef __attribute__((ext_vector_type(8))) short bf16x8;   // 8 bf16 = 4 VGPR
typedef __attribute__((ext_vector_type(4))) float f32x4;    // MFMA accumulator

__device__ __forceinline__ float4 ld4(const float* p) { return *reinterpret_cast<const float4*>(p); }

// float -> bf16 (RNE) and back
__device__ __forceinline__ unsigned short f2bf(float f) {
  unsigned int u = __float_as_uint(f);
  u += 0x7fffu + ((u >> 16) & 1u);
  return (unsigned short)(u >> 16);
}
__device__ __forceinline__ float bf2f(unsigned short s) {
  return __uint_as_float(((unsigned int)s) << 16);
}

// ---------------------------------------------------------------------------
// K0: pre-pass (one-time weight conversion).
// ---------------------------------------------------------------------------
__global__ __launch_bounds__(256) void k_prep(
    const float* __restrict__ ew1, const float* __restrict__ type_emb,
    const float* __restrict__ mw1, const float* __restrict__ mw2,
    unsigned short* __restrict__ Wab, unsigned short* __restrict__ Wbb,
    unsigned short* __restrict__ Wcb,
    unsigned short* __restrict__ m1h, unsigned short* __restrict__ m1l,
    unsigned short* __restrict__ m2h, unsigned short* __restrict__ m2l,
    float* __restrict__ tvg)
{
  int g = blockIdx.x * 256 + threadIdx.x;   // 0..16383
  int o = g >> 7, k = g & 127;
  Wab[g] = f2bf(ew1[o * IND + k]);
  Wbb[g] = f2bf(ew1[o * IND + 128 + k]);
  Wcb[g] = f2bf(ew1[o * IND + 256 + k]);
  float w1 = mw1[g];
  unsigned short h1 = f2bf(w1);
  m1h[g] = h1; m1l[g] = f2bf(w1 - bf2f(h1));
  float w2 = mw2[g];
  unsigned short h2 = f2bf(w2);
  m2h[g] = h2; m2l[g] = f2bf(w2 - bf2f(h2));
  if (blockIdx.x == 0) {
    int t = threadIdx.x, oo = t & 127, ty = t >> 7;
    float s = 0.f;
#pragma unroll
    for (int j = 0; j < 8; ++j) s += ew1[oo * IND + 384 + j] * type_emb[ty * 8 + j];
    tvg[ty * 128 + oo] = s;
  }
}

// ---------------------------------------------------------------------------
// MFMA micro-GEMM: acc[nt] += X-tile(rows me..me+15) . W^T  (K=128)
// TERMS=2: (Xh+Xl).Wh ; TERMS=3: Xh.Wh + Xl.Wh + Xh.Wl (f32-class)
// ---------------------------------------------------------------------------
template <int TERMS>
__device__ __forceinline__ void mm_acc(
    const unsigned short (*Xh)[136], const unsigned short (*Xl)[136],
    const unsigned short (*Wh)[136], const unsigned short (*Wl)[136],
    int me, int r, int q, f32x4 acc[8])
{
#pragma unroll
  for (int ks = 0; ks < 4; ++ks) {
    bf16x8 ah = *reinterpret_cast<const bf16x8*>(&Xh[me + r][ks * 32 + q * 8]);
    bf16x8 al = *reinterpret_cast<const bf16x8*>(&Xl[me + r][ks * 32 + q * 8]);
#pragma unroll
    for (int nt = 0; nt < 8; ++nt) {
      bf16x8 bh = *reinterpret_cast<const bf16x8*>(&Wh[nt * 16 + r][ks * 32 + q * 8]);
      acc[nt] = __builtin_amdgcn_mfma_f32_16x16x32_bf16(ah, bh, acc[nt], 0, 0, 0);
      acc[nt] = __builtin_amdgcn_mfma_f32_16x16x32_bf16(al, bh, acc[nt], 0, 0, 0);
      if (TERMS == 3) {
        bf16x8 bl = *reinterpret_cast<const bf16x8*>(&Wl[nt * 16 + r][ks * 32 + q * 8]);
        acc[nt] = __builtin_amdgcn_mfma_f32_16x16x32_bf16(ah, bl, acc[nt], 0, 0, 0);
      }
    }
  }
}

// ---------------------------------------------------------------------------
// K1: per-node precompute via MFMA. 128 nodes/block, 8 waves.
//   Ab = bf16(z.Wa^T), Bb = bf16(z.Wb^T), Mb = bf16(M), zb = bf16(z)
// ---------------------------------------------------------------------------
__global__ __launch_bounds__(512, 1) void k_node_mfma(
    const float* __restrict__ z,
    const unsigned short* __restrict__ Wab, const unsigned short* __restrict__ Wbb,
    const unsigned short* __restrict__ m1h, const unsigned short* __restrict__ m1l,
    const unsigned short* __restrict__ m2h, const unsigned short* __restrict__ m2l,
    const float* __restrict__ mb1, const float* __restrict__ mb2,
    unsigned short* __restrict__ Ab, unsigned short* __restrict__ Bb,
    unsigned short* __restrict__ Mb, unsigned short* __restrict__ zb)
{
  __shared__ unsigned short Xh[128][136], Xl[128][136];
  __shared__ unsigned short Wh[128][136], Wl[136][136];
  const int t  = threadIdx.x;
  const int n0 = blockIdx.x * 128;

  // stage z, split hi/lo; also write zb = bf16(z)
#pragma unroll
  for (int it = 0; it < 8; ++it) {
    int f = it * 512 + t, rr = f >> 5, c4 = (f & 31) * 4;
    int n = n0 + rr; if (n >= NN) n = NN - 1;
    float4 v = ld4(&z[(size_t)n * D + c4]);
    ushort4 hi, lo;
    hi.x = f2bf(v.x); lo.x = f2bf(v.x - bf2f(hi.x));
    hi.y = f2bf(v.y); lo.y = f2bf(v.y - bf2f(hi.y));
    hi.z = f2bf(v.z); lo.z = f2bf(v.z - bf2f(hi.z));
    hi.w = f2bf(v.w); lo.w = f2bf(v.w - bf2f(hi.w));
    *reinterpret_cast<ushort4*>(&Xh[rr][c4]) = hi;
    *reinterpret_cast<ushort4*>(&Xl[rr][c4]) = lo;
    if (n0 + rr < NN)
      *reinterpret_cast<ushort4*>(&zb[(size_t)(n0 + rr) * D + c4]) = hi;
  }
#pragma unroll
  for (int it = 0; it < 4; ++it) {
    int f = it * 512 + t, row = f >> 4, c8 = (f & 15) * 8;
    *reinterpret_cast<bf16x8*>(&Wh[row][c8]) =
        *reinterpret_cast<const bf16x8*>(&Wab[row * 128 + c8]);
  }
  __syncthreads();

  const int l = t & 63, q = l >> 4, r = l & 15;
  const int me = (t >> 6) * 16;

  f32x4 acc[8];

  // ---- A ----
#pragma unroll
  for (int nt = 0; nt < 8; ++nt) acc[nt] = (f32x4){0.f, 0.f, 0.f, 0.f};
  mm_acc<2>(Xh, Xl, Wh, Wl, me, r, q, acc);
#pragma unroll
  for (int nt = 0; nt < 8; ++nt)
#pragma unroll
    for (int i = 0; i < 4; ++i) {
      int n = n0 + me + q * 4 + i;
      if (n < NN) Ab[(size_t)n * D + nt * 16 + r] = f2bf(acc[nt][i]);
    }
  __syncthreads();

  // ---- B ----
#pragma unroll
  for (int it = 0; it < 4; ++it) {
    int f = it * 512 + t, row = f >> 4, c8 = (f & 15) * 8;
    *reinterpret_cast<bf16x8*>(&Wh[row][c8]) =
        *reinterpret_cast<const bf16x8*>(&Wbb[row * 128 + c8]);
  }
  __syncthreads();
#pragma unroll
  for (int nt = 0; nt < 8; ++nt) acc[nt] = (f32x4){0.f, 0.f, 0.f, 0.f};
  mm_acc<2>(Xh, Xl, Wh, Wl, me, r, q, acc);
#pragma unroll
  for (int nt = 0; nt < 8; ++nt)
#pragma unroll
    for (int i = 0; i < 4; ++i) {
      int n = n0 + me + q * 4 + i;
      if (n < NN) Bb[(size_t)n * D + nt * 16 + r] = f2bf(acc[nt][i]);
    }
  __syncthreads();

  // ---- M layer 1: h1 = relu(mw1.z + mb1), split back into Xh/Xl ----
#pragma unroll
  for (int it = 0; it < 4; ++it) {
    int f = it * 512 + t, row = f >> 4, c8 = (f & 15) * 8;
    *reinterpret_cast<bf16x8*>(&Wh[row][c8]) =
        *reinterpret_cast<const bf16x8*>(&m1h[row * 128 + c8]);
    *reinterpret_cast<bf16x8*>(&Wl[row][c8]) =
        *reinterpret_cast<const bf16x8*>(&m1l[row * 128 + c8]);
  }
  __syncthreads();
#pragma unroll
  for (int nt = 0; nt < 8; ++nt) acc[nt] = (f32x4){0.f, 0.f, 0.f, 0.f};
  mm_acc<3>(Xh, Xl, Wh, Wl, me, r, q, acc);
#pragma unroll
  for (int nt = 0; nt < 8; ++nt) {
    int col = nt * 16 + r;
    float b1 = mb1[col];
#pragma unroll
    for (int i = 0; i < 4; ++i) {
      float h = fmaxf(acc[nt][i] + b1, 0.0f);
      unsigned short hh = f2bf(h);
      Xh[me + q * 4 + i][col] = hh;
      Xl[me + q * 4 + i][col] = f2bf(h - bf2f(hh));
    }
  }
  __syncthreads();

  // ---- M layer 2: M = h1.mw2^T + mb2, stored bf16 ----
#pragma unroll
  for (int it = 0; it < 4; ++it) {
    int f = it * 512 + t, row = f >> 4, c8 = (f & 15) * 8;
    *reinterpret_cast<bf16x8*>(&Wh[row][c8]) =
        *reinterpret_cast<const bf16x8*>(&m2h[row * 128 + c8]);
    *reinterpret_cast<bf16x8*>(&Wl[row][c8]) =
        *reinterpret_cast<const bf16x8*>(&m2l[row * 128 + c8]);
  }
  __syncthreads();
#pragma unroll
  for (int nt = 0; nt < 8; ++nt) acc[nt] = (f32x4){0.f, 0.f, 0.f, 0.f};
  mm_acc<3>(Xh, Xl, Wh, Wl, me, r, q, acc);
#pragma unroll
  for (int nt = 0; nt < 8; ++nt) {
    int col = nt * 16 + r;
    float b2 = mb2[col];
#pragma unroll
    for (int i = 0; i < 4; ++i) {
      int n = n0 + me + q * 4 + i;
      if (n < NN) Mb[(size_t)n * D + col] = f2bf(acc[nt][i] + b2);
    }
  }
}

// ---------------------------------------------------------------------------
// CSR build: histogram -> two-level parallel scan -> fill
// ---------------------------------------------------------------------------
constexpr int SNB = 196;   // scan blocks: 196*256 = 50176 >= NN

__global__ __launch_bounds__(256) void k_hist(const int* __restrict__ ei,
                                              int* __restrict__ deg)
{
  int e = blockIdx.x * 256 + threadIdx.x;
  if (e < NE) atomicAdd(&deg[ei[e]], 1);
}

// block-local exclusive scan; pre[i] = exclusive prefix within block, bsum[b] = block total
__global__ __launch_bounds__(256) void k_scan1(const int* __restrict__ deg,
                                               int* __restrict__ pre,
                                               int* __restrict__ bsum)
{
  __shared__ int ps[256];
  const int t = threadIdx.x, b = blockIdx.x;
  const int i = b * 256 + t;
  int v = (i < NN) ? deg[i] : 0;
  ps[t] = v;
  __syncthreads();
  for (int off = 1; off < 256; off <<= 1) {
    int u = (t >= off) ? ps[t - off] : 0;
    __syncthreads();
    ps[t] += u;
    __syncthreads();
  }
  pre[i] = ps[t] - v;               // exclusive
  if (t == 255) bsum[b] = ps[255];  // block total
}

// single block: exclusive scan of SNB block sums
__global__ __launch_bounds__(256) void k_scan2(const int* __restrict__ bsum,
                                               int* __restrict__ bbase)
{
  __shared__ int ps[256];
  const int t = threadIdx.x;
  int v = (t < SNB) ? bsum[t] : 0;
  ps[t] = v;
  __syncthreads();
  for (int off = 1; off < 256; off <<= 1) {
    int u = (t >= off) ? ps[t - off] : 0;
    __syncthreads();
    ps[t] += u;
    __syncthreads();
  }
  if (t < SNB) bbase[t] = ps[t] - v;  // exclusive
}

// add block base -> rowptr + cursor
__global__ __launch_bounds__(256) void k_scan3(const int* __restrict__ pre,
                                               const int* __restrict__ bbase,
                                               int* __restrict__ rowptr,
                                               int* __restrict__ cursor)
{
  const int t = threadIdx.x, b = blockIdx.x;
  const int i = b * 256 + t;
  if (i < NN) {
    int v = pre[i] + bbase[b];
    rowptr[i] = v;
    cursor[i] = v;
  }
  if (i == 0) rowptr[NN] = NE;
}

__global__ __launch_bounds__(256) void k_fill(const int* __restrict__ ei,
                                              int* __restrict__ cursor,
                                              int* __restrict__ eid,
                                              int* __restrict__ de_perm)
{
  int e = blockIdx.x * 256 + threadIdx.x;
  if (e < NE) {
    int pos = atomicAdd(&cursor[ei[e]], 1);
    eid[pos] = e;
    de_perm[pos] = ei[NE + e];
  }
}

// ---------------------------------------------------------------------------
// K2: per-edge pass, bf16 MFMA, bf16 gathers. 128 edges/block, 8 waves, CSR
// order with XCD-aware block swizzle.
// ---------------------------------------------------------------------------
__global__ __launch_bounds__(512, 4) void k_edge_mfma(
    const unsigned short* __restrict__ zb, const int* __restrict__ ei,
    const int* __restrict__ etype,
    const unsigned short* __restrict__ Wcb, const float* __restrict__ tvg,
    const float* __restrict__ eb1, const float* __restrict__ ew2,
    const float* __restrict__ eb2,
    const unsigned short* __restrict__ Ab, const unsigned short* __restrict__ Bb,
    const int* __restrict__ eid, const int* __restrict__ de_perm,
    float* __restrict__ wexp_perm)
{
  __shared__ unsigned short Xb[128][136];
  __shared__ unsigned short Wb[128][136];
  __shared__ int se[128], de[128], tye[128];

  const int t = threadIdx.x;
  // XCD swizzle (grid 4688 % 8 == 0 -> simple bijective form)
  const int nx  = gridDim.x >> 3;
  const int swz = (blockIdx.x & 7) * nx + (blockIdx.x >> 3);
  const int e0  = swz * 128;

  if (t < 128) {
    int pos = e0 + t;
    if (pos < NE) {
      int e  = eid[pos];
      se[t]  = ei[e];
      de[t]  = de_perm[pos];
      tye[t] = etype[e];
    } else { se[t] = 0; de[t] = 0; tye[t] = 0; }
  }
#pragma unroll
  for (int it = 0; it < 4; ++it) {
    int f = it * 512 + t, row = f >> 4, c8 = (f & 15) * 8;
    *reinterpret_cast<bf16x8*>(&Wb[row][c8]) =
        *reinterpret_cast<const bf16x8*>(&Wcb[row * 128 + c8]);
  }
  __syncthreads();

  // stage |zb[src]-zb[dst]| (bf16 gathers: 256B/row)
#pragma unroll
  for (int it = 0; it < 8; ++it) {
    int f = it * 512 + t, r = f >> 5, c4 = (f & 31) * 4;
    ushort4 a = *reinterpret_cast<const ushort4*>(&zb[(size_t)se[r] * D + c4]);
    ushort4 b = *reinterpret_cast<const ushort4*>(&zb[(size_t)de[r] * D + c4]);
    ushort4 v;
    v.x = f2bf(fabsf(bf2f(a.x) - bf2f(b.x)));
    v.y = f2bf(fabsf(bf2f(a.y) - bf2f(b.y)));
    v.z = f2bf(fabsf(bf2f(a.z) - bf2f(b.z)));
    v.w = f2bf(fabsf(bf2f(a.w) - bf2f(b.w)));
    *reinterpret_cast<ushort4*>(&Xb[r][c4]) = v;
  }
  __syncthreads();

  const int l = t & 63, q = l >> 4, r = l & 15;
  const int me = (t >> 6) * 16;

  f32x4 acc[8];
#pragma unroll
  for (int nt = 0; nt < 8; ++nt) acc[nt] = (f32x4){0.f, 0.f, 0.f, 0.f};

#pragma unroll
  for (int ks = 0; ks < 4; ++ks) {
    bf16x8 a = *reinterpret_cast<const bf16x8*>(&Xb[me + r][ks * 32 + q * 8]);
#pragma unroll
    for (int nt = 0; nt < 8; ++nt) {
      bf16x8 b = *reinterpret_cast<const bf16x8*>(&Wb[nt * 16 + r][ks * 32 + q * 8]);
      acc[nt] = __builtin_amdgcn_mfma_f32_16x16x32_bf16(a, b, acc[nt], 0, 0, 0);
    }
  }

  int s[4], dd[4], ty[4];
#pragma unroll
  for (int i = 0; i < 4; ++i) {
    int el = me + q * 4 + i;
    s[i] = se[el]; dd[i] = de[el]; ty[i] = tye[el];
  }
  float p[4] = {0.f, 0.f, 0.f, 0.f};
#pragma unroll
  for (int nt = 0; nt < 8; ++nt) {
    int col = nt * 16 + r;
    float e1  = eb1[col], w2 = ew2[col];
    float tva = tvg[col], tvb = tvg[128 + col];
#pragma unroll
    for (int i = 0; i < 4; ++i) {
      float h = acc[nt][i] + bf2f(Ab[(size_t)s[i] * D + col])
              + bf2f(Bb[(size_t)dd[i] * D + col]) + (ty[i] ? tvb : tva) + e1;
      p[i] += fmaxf(h, 0.f) * w2;
    }
  }
#pragma unroll
  for (int m = 1; m < 16; m <<= 1) {
#pragma unroll
    for (int i = 0; i < 4; ++i) p[i] += __shfl_xor(p[i], m);
  }
  if (r == 0) {
    float b2 = eb2[0];
#pragma unroll
    for (int i = 0; i < 4; ++i) {
      int pos = e0 + me + q * 4 + i;
      if (pos < NE) {
        float w = 1.0f / (1.0f + expf(-(p[i] + b2)));  // sigmoid
        wexp_perm[pos] = expf(w);                      // w in (0,1): stable
      }
    }
  }
}

// ---------------------------------------------------------------------------
// K3: fused per-node aggregation + residual + LayerNorm (unchanged).
// ---------------------------------------------------------------------------
__global__ __launch_bounds__(256) void k_agg(
    const float* __restrict__ z, const float* __restrict__ wexp_perm,
    const unsigned short* __restrict__ Mb, const int* __restrict__ rowptr,
    const int* __restrict__ eid, const int* __restrict__ de_perm,
    const float* __restrict__ gamma, const float* __restrict__ beta,
    float* __restrict__ out, float* __restrict__ alpha_out)
{
  const int t = threadIdx.x;
  const int n = blockIdx.x * 4 + (t >> 6);
  const int l = t & 63;
  const int start = rowptr[n], end = rowptr[n + 1];

  float tot = 0.f;
  for (int base = start; base < end; base += 64) {
    if (base + l < end) tot += wexp_perm[base + l];
  }
#pragma unroll
  for (int off = 32; off; off >>= 1) tot += __shfl_xor(tot, off);
  const float inv = 1.0f / (tot + 1e-12f);

  float2 acc = make_float2(0.f, 0.f);
  for (int base = start; base < end; base += 64) {
    int cnt = min(64, end - base);
    int dd = 0;
    float al = 0.f;
    if (l < cnt) {
      int pos = base + l;
      al = wexp_perm[pos] * inv;
      dd = de_perm[pos];
      alpha_out[eid[pos]] = al;
    }
    for (int i = 0; i < cnt; ++i) {
      float a = __shfl(al, i);
      int   d = __shfl(dd, i);
      ushort2 m = *reinterpret_cast<const ushort2*>(&Mb[(size_t)d * D + l * 2]);
      acc.x = fmaf(a, bf2f(m.x), acc.x);
      acc.y = fmaf(a, bf2f(m.y), acc.y);
    }
  }

  float2 xz = *reinterpret_cast<const float2*>(&z[(size_t)n * D + l * 2]);
  float x0 = xz.x + acc.x, x1 = xz.y + acc.y;
  float s = x0 + x1;
#pragma unroll
  for (int off = 32; off; off >>= 1) s += __shfl_xor(s, off);
  const float mu = s * (1.0f / 128.0f);
  float d0 = x0 - mu, d1 = x1 - mu;
  float q = d0 * d0 + d1 * d1;
#pragma unroll
  for (int off = 32; off; off >>= 1) q += __shfl_xor(q, off);
  const float rstd = rsqrtf(q * (1.0f / 128.0f) + 1e-5f);
  float2 g = *reinterpret_cast<const float2*>(&gamma[l * 2]);
  float2 b = *reinterpret_cast<const float2*>(&beta[l * 2]);
  float2 o = make_float2(d0 * rstd * g.x + b.x, d1 * rstd * g.y + b.y);
  *reinterpret_cast<float2*>(&out[(size_t)n * D + l * 2]) = o;
}

// ---------------------------------------------------------------------------
extern "C" void kernel_launch(void* const* d_in, const int* in_sizes, int n_in,
                              void* d_out, int out_size, void* d_ws, size_t ws_size,
                              hipStream_t stream)
{
  const float* z        = (const float*)d_in[0];
  const int*   ei       = (const int*)d_in[1];   // [2,E]: src row, then dst row
  const int*   etype    = (const int*)d_in[2];
  const float* type_emb = (const float*)d_in[3];
  const float* ew1      = (const float*)d_in[4];
  const float* eb1      = (const float*)d_in[5];
  const float* ew2      = (const float*)d_in[6];
  const float* eb2      = (const float*)d_in[7];
  const float* mw1      = (const float*)d_in[8];
  const float* mb1      = (const float*)d_in[9];
  const float* mw2      = (const float*)d_in[10];
  const float* mb2      = (const float*)d_in[11];
  const float* gamma    = (const float*)d_in[12];
  const float* beta     = (const float*)d_in[13];

  // workspace (float-unit offsets):
  // Ab|Bb|Mb|zb (bf16) | wexp_perm | ints | bf16 weights | tvg | scan temps
  float*          ws        = (float*)d_ws;
  unsigned short* Ab        = (unsigned short*)(ws);
  unsigned short* Bb        = (unsigned short*)(ws + 3200000);
  unsigned short* Mb        = (unsigned short*)(ws + 6400000);
  unsigned short* zb        = (unsigned short*)(ws + 9600000);
  float*          wexp_perm = ws + 12800000;
  int*            deg       = (int*)(ws + 13400000);
  int*            rowptr    = deg + 50000;
  int*            cursor    = rowptr + 50004;
  int*            eid       = cursor + 50000;
  int*            de_perm   = eid + 600000;
  unsigned short* Wcb       = (unsigned short*)(ws + 14800000);
  float*          tvg       = ws + 14810000;
  unsigned short* Wab       = (unsigned short*)(ws + 14820000);
  unsigned short* Wbb       = (unsigned short*)(ws + 14830000);
  unsigned short* m1h       = (unsigned short*)(ws + 14840000);
  unsigned short* m1l       = (unsigned short*)(ws + 14850000);
  unsigned short* m2h       = (unsigned short*)(ws + 14860000);
  unsigned short* m2l       = (unsigned short*)(ws + 14870000);
  int*            pre       = (int*)(ws + 14880000);   // 50176 ints
  int*            bsum      = (int*)(ws + 14940000);   // 256
  int*            bbase     = (int*)(ws + 14941000);   // 256

  float* out       = (float*)d_out;
  float* alpha_out = out + (size_t)NN * D;

  hipMemsetAsync(deg, 0, 50000 * sizeof(int), stream);

  k_prep<<<64, 256, 0, stream>>>(ew1, type_emb, mw1, mw2,
                                 Wab, Wbb, Wcb, m1h, m1l, m2h, m2l, tvg);
  k_hist<<<(NE + 255) / 256, 256, 0, stream>>>(ei, deg);
  k_scan1<<<SNB, 256, 0, stream>>>(deg, pre, bsum);
  k_scan2<<<1, 256, 0, stream>>>(bsum, bbase);
  k_scan3<<<SNB, 256, 0, stream>>>(pre, bbase, rowptr, cursor);
  k_fill<<<(NE + 255) / 256, 256, 0, stream>>>(ei, cursor, eid, de_perm);
  k_node_mfma<<<(NN + 127) / 128, 512, 0, stream>>>(z, Wab, Wbb, m1h, m1l,
                                                    m2h, m2l, mb1, mb2,
                                                    Ab, Bb, Mb, zb);
  k_edge_mfma<<<(NE + 127) / 128, 512, 0, stream>>>(zb, ei, etype, Wcb, tvg,
                                                    eb1, ew2, eb2, Ab, Bb,
                                                    eid, de_perm, wexp_perm);
  k_agg<<<NN / 4, 256, 0, stream>>>(z, wexp_perm, Mb, rowptr, eid, de_perm,
                                    gamma, beta, out, alpha_out);
}

// Round 10
// 261.999 us; speedup vs baseline: 12.0292x; 1.0418x over previous
//
#include <hip/hip_runtime.h>
#include <math.h>

// Problem constants (fixed by the reference)
constexpr int NN  = 50000;   // nodes
constexpr int NE  = 600000;  // edges
constexpr int D   = 128;     // DIM == HID
constexpr int IND = 392;     // 3*DIM + TEMB

typedef __attribute__((ext_vector_type(8))) short bf16x8;   // 8 bf16 = 4 VGPR
typedef __attribute__((ext_vector_type(4))) float f32x4;    // MFMA accumulator

__device__ __forceinline__ float4 ld4(const float* p) { return *reinterpret_cast<const float4*>(p); }

// float -> bf16 (RNE) and back
__device__ __forceinline__ unsigned short f2bf(float f) {
  unsigned int u = __float_as_uint(f);
  u += 0x7fffu + ((u >> 16) & 1u);
  return (unsigned short)(u >> 16);
}
__device__ __forceinline__ float bf2f(unsigned short s) {
  return __uint_as_float(((unsigned int)s) << 16);
}

// ---------------------------------------------------------------------------
// K0: pre-pass (one-time weight conversion).
// ---------------------------------------------------------------------------
__global__ __launch_bounds__(256) void k_prep(
    const float* __restrict__ ew1, const float* __restrict__ type_emb,
    const float* __restrict__ mw1, const float* __restrict__ mw2,
    unsigned short* __restrict__ Wab, unsigned short* __restrict__ Wbb,
    unsigned short* __restrict__ Wcb,
    unsigned short* __restrict__ m1h, unsigned short* __restrict__ m1l,
    unsigned short* __restrict__ m2h, unsigned short* __restrict__ m2l,
    float* __restrict__ tvg)
{
  int g = blockIdx.x * 256 + threadIdx.x;   // 0..16383
  int o = g >> 7, k = g & 127;
  Wab[g] = f2bf(ew1[o * IND + k]);
  Wbb[g] = f2bf(ew1[o * IND + 128 + k]);
  Wcb[g] = f2bf(ew1[o * IND + 256 + k]);
  float w1 = mw1[g];
  unsigned short h1 = f2bf(w1);
  m1h[g] = h1; m1l[g] = f2bf(w1 - bf2f(h1));
  float w2 = mw2[g];
  unsigned short h2 = f2bf(w2);
  m2h[g] = h2; m2l[g] = f2bf(w2 - bf2f(h2));
  if (blockIdx.x == 0) {
    int t = threadIdx.x, oo = t & 127, ty = t >> 7;
    float s = 0.f;
#pragma unroll
    for (int j = 0; j < 8; ++j) s += ew1[oo * IND + 384 + j] * type_emb[ty * 8 + j];
    tvg[ty * 128 + oo] = s;
  }
}

// ---------------------------------------------------------------------------
// MFMA micro-GEMM (k_node): acc[nt] += X-tile(rows me..me+15) . W^T  (K=128)
// TERMS=1: Xh.Wh ; TERMS=2: (Xh+Xl).Wh ; TERMS=3: + Xh.Wl
// ---------------------------------------------------------------------------
template <int TERMS>
__device__ __forceinline__ void mm_acc(
    const unsigned short (*Xh)[136], const unsigned short (*Xl)[136],
    const unsigned short (*Wh)[136], const unsigned short (*Wl)[136],
    int me, int r, int q, f32x4 acc[8])
{
#pragma unroll
  for (int ks = 0; ks < 4; ++ks) {
    bf16x8 ah = *reinterpret_cast<const bf16x8*>(&Xh[me + r][ks * 32 + q * 8]);
    bf16x8 al;
    if (TERMS >= 2) al = *reinterpret_cast<const bf16x8*>(&Xl[me + r][ks * 32 + q * 8]);
#pragma unroll
    for (int nt = 0; nt < 8; ++nt) {
      bf16x8 bh = *reinterpret_cast<const bf16x8*>(&Wh[nt * 16 + r][ks * 32 + q * 8]);
      acc[nt] = __builtin_amdgcn_mfma_f32_16x16x32_bf16(ah, bh, acc[nt], 0, 0, 0);
      if (TERMS >= 2)
        acc[nt] = __builtin_amdgcn_mfma_f32_16x16x32_bf16(al, bh, acc[nt], 0, 0, 0);
      if (TERMS == 3) {
        bf16x8 bl = *reinterpret_cast<const bf16x8*>(&Wl[nt * 16 + r][ks * 32 + q * 8]);
        acc[nt] = __builtin_amdgcn_mfma_f32_16x16x32_bf16(ah, bl, acc[nt], 0, 0, 0);
      }
    }
  }
}

// ---------------------------------------------------------------------------
// K1: per-node precompute via MFMA. 128 nodes/block, 8 waves.
//   Ab = bf16(z.Wa^T) (1-term), Bb = bf16(z.Wb^T) (1-term),
//   Mb = bf16(M) (3-term, f32-class), zb = bf16(z)
// ---------------------------------------------------------------------------
__global__ __launch_bounds__(512, 1) void k_node_mfma(
    const float* __restrict__ z,
    const unsigned short* __restrict__ Wab, const unsigned short* __restrict__ Wbb,
    const unsigned short* __restrict__ m1h, const unsigned short* __restrict__ m1l,
    const unsigned short* __restrict__ m2h, const unsigned short* __restrict__ m2l,
    const float* __restrict__ mb1, const float* __restrict__ mb2,
    unsigned short* __restrict__ Ab, unsigned short* __restrict__ Bb,
    unsigned short* __restrict__ Mb, unsigned short* __restrict__ zb)
{
  __shared__ unsigned short Xh[128][136], Xl[128][136];
  __shared__ unsigned short Wh[128][136], Wl[128][136];
  const int t  = threadIdx.x;
  const int n0 = blockIdx.x * 128;

  // stage z, split hi/lo; also write zb = bf16(z)
#pragma unroll
  for (int it = 0; it < 8; ++it) {
    int f = it * 512 + t, rr = f >> 5, c4 = (f & 31) * 4;
    int n = n0 + rr; if (n >= NN) n = NN - 1;
    float4 v = ld4(&z[(size_t)n * D + c4]);
    ushort4 hi, lo;
    hi.x = f2bf(v.x); lo.x = f2bf(v.x - bf2f(hi.x));
    hi.y = f2bf(v.y); lo.y = f2bf(v.y - bf2f(hi.y));
    hi.z = f2bf(v.z); lo.z = f2bf(v.z - bf2f(hi.z));
    hi.w = f2bf(v.w); lo.w = f2bf(v.w - bf2f(hi.w));
    *reinterpret_cast<ushort4*>(&Xh[rr][c4]) = hi;
    *reinterpret_cast<ushort4*>(&Xl[rr][c4]) = lo;
    if (n0 + rr < NN)
      *reinterpret_cast<ushort4*>(&zb[(size_t)(n0 + rr) * D + c4]) = hi;
  }
#pragma unroll
  for (int it = 0; it < 4; ++it) {
    int f = it * 512 + t, row = f >> 4, c8 = (f & 15) * 8;
    *reinterpret_cast<bf16x8*>(&Wh[row][c8]) =
        *reinterpret_cast<const bf16x8*>(&Wab[row * 128 + c8]);
  }
  __syncthreads();

  const int l = t & 63, q = l >> 4, r = l & 15;
  const int me = (t >> 6) * 16;

  f32x4 acc[8];

  // ---- A (1-term: bf16 z x bf16 W; alpha-path, tolerant) ----
#pragma unroll
  for (int nt = 0; nt < 8; ++nt) acc[nt] = (f32x4){0.f, 0.f, 0.f, 0.f};
  mm_acc<1>(Xh, Xl, Wh, Wl, me, r, q, acc);
#pragma unroll
  for (int nt = 0; nt < 8; ++nt)
#pragma unroll
    for (int i = 0; i < 4; ++i) {
      int n = n0 + me + q * 4 + i;
      if (n < NN) Ab[(size_t)n * D + nt * 16 + r] = f2bf(acc[nt][i]);
    }
  __syncthreads();

  // ---- B (1-term) ----
#pragma unroll
  for (int it = 0; it < 4; ++it) {
    int f = it * 512 + t, row = f >> 4, c8 = (f & 15) * 8;
    *reinterpret_cast<bf16x8*>(&Wh[row][c8]) =
        *reinterpret_cast<const bf16x8*>(&Wbb[row * 128 + c8]);
  }
  __syncthreads();
#pragma unroll
  for (int nt = 0; nt < 8; ++nt) acc[nt] = (f32x4){0.f, 0.f, 0.f, 0.f};
  mm_acc<1>(Xh, Xl, Wh, Wl, me, r, q, acc);
#pragma unroll
  for (int nt = 0; nt < 8; ++nt)
#pragma unroll
    for (int i = 0; i < 4; ++i) {
      int n = n0 + me + q * 4 + i;
      if (n < NN) Bb[(size_t)n * D + nt * 16 + r] = f2bf(acc[nt][i]);
    }
  __syncthreads();

  // ---- M layer 1: h1 = relu(mw1.z + mb1), split back into Xh/Xl ----
#pragma unroll
  for (int it = 0; it < 4; ++it) {
    int f = it * 512 + t, row = f >> 4, c8 = (f & 15) * 8;
    *reinterpret_cast<bf16x8*>(&Wh[row][c8]) =
        *reinterpret_cast<const bf16x8*>(&m1h[row * 128 + c8]);
    *reinterpret_cast<bf16x8*>(&Wl[row][c8]) =
        *reinterpret_cast<const bf16x8*>(&m1l[row * 128 + c8]);
  }
  __syncthreads();
#pragma unroll
  for (int nt = 0; nt < 8; ++nt) acc[nt] = (f32x4){0.f, 0.f, 0.f, 0.f};
  mm_acc<3>(Xh, Xl, Wh, Wl, me, r, q, acc);
#pragma unroll
  for (int nt = 0; nt < 8; ++nt) {
    int col = nt * 16 + r;
    float b1 = mb1[col];
#pragma unroll
    for (int i = 0; i < 4; ++i) {
      float h = fmaxf(acc[nt][i] + b1, 0.0f);
      unsigned short hh = f2bf(h);
      Xh[me + q * 4 + i][col] = hh;
      Xl[me + q * 4 + i][col] = f2bf(h - bf2f(hh));
    }
  }
  __syncthreads();

  // ---- M layer 2: M = h1.mw2^T + mb2, stored bf16 ----
#pragma unroll
  for (int it = 0; it < 4; ++it) {
    int f = it * 512 + t, row = f >> 4, c8 = (f & 15) * 8;
    *reinterpret_cast<bf16x8*>(&Wh[row][c8]) =
        *reinterpret_cast<const bf16x8*>(&m2h[row * 128 + c8]);
    *reinterpret_cast<bf16x8*>(&Wl[row][c8]) =
        *reinterpret_cast<const bf16x8*>(&m2l[row * 128 + c8]);
  }
  __syncthreads();
#pragma unroll
  for (int nt = 0; nt < 8; ++nt) acc[nt] = (f32x4){0.f, 0.f, 0.f, 0.f};
  mm_acc<3>(Xh, Xl, Wh, Wl, me, r, q, acc);
#pragma unroll
  for (int nt = 0; nt < 8; ++nt) {
    int col = nt * 16 + r;
    float b2 = mb2[col];
#pragma unroll
    for (int i = 0; i < 4; ++i) {
      int n = n0 + me + q * 4 + i;
      if (n < NN) Mb[(size_t)n * D + col] = f2bf(acc[nt][i] + b2);
    }
  }
}

// ---------------------------------------------------------------------------
// CSR build: histogram -> two-level parallel scan -> fill
// ---------------------------------------------------------------------------
constexpr int SNB = 196;   // scan blocks: 196*256 = 50176 >= NN

__global__ __launch_bounds__(256) void k_hist(const int* __restrict__ ei,
                                              int* __restrict__ deg)
{
  int e = blockIdx.x * 256 + threadIdx.x;
  if (e < NE) atomicAdd(&deg[ei[e]], 1);
}

__global__ __launch_bounds__(256) void k_scan1(const int* __restrict__ deg,
                                               int* __restrict__ pre,
                                               int* __restrict__ bsum)
{
  __shared__ int ps[256];
  const int t = threadIdx.x, b = blockIdx.x;
  const int i = b * 256 + t;
  int v = (i < NN) ? deg[i] : 0;
  ps[t] = v;
  __syncthreads();
  for (int off = 1; off < 256; off <<= 1) {
    int u = (t >= off) ? ps[t - off] : 0;
    __syncthreads();
    ps[t] += u;
    __syncthreads();
  }
  pre[i] = ps[t] - v;               // exclusive
  if (t == 255) bsum[b] = ps[255];  // block total
}

__global__ __launch_bounds__(256) void k_scan2(const int* __restrict__ bsum,
                                               int* __restrict__ bbase)
{
  __shared__ int ps[256];
  const int t = threadIdx.x;
  int v = (t < SNB) ? bsum[t] : 0;
  ps[t] = v;
  __syncthreads();
  for (int off = 1; off < 256; off <<= 1) {
    int u = (t >= off) ? ps[t - off] : 0;
    __syncthreads();
    ps[t] += u;
    __syncthreads();
  }
  if (t < SNB) bbase[t] = ps[t] - v;  // exclusive
}

__global__ __launch_bounds__(256) void k_scan3(const int* __restrict__ pre,
                                               const int* __restrict__ bbase,
                                               int* __restrict__ rowptr,
                                               int* __restrict__ cursor)
{
  const int t = threadIdx.x, b = blockIdx.x;
  const int i = b * 256 + t;
  if (i < NN) {
    int v = pre[i] + bbase[b];
    rowptr[i] = v;
    cursor[i] = v;
  }
  if (i == 0) rowptr[NN] = NE;
}

__global__ __launch_bounds__(256) void k_fill(const int* __restrict__ ei,
                                              int* __restrict__ cursor,
                                              int* __restrict__ eid,
                                              int* __restrict__ de_perm)
{
  int e = blockIdx.x * 256 + threadIdx.x;
  if (e < NE) {
    int pos = atomicAdd(&cursor[ei[e]], 1);
    eid[pos] = e;
    de_perm[pos] = ei[NE + e];
  }
}

// ---------------------------------------------------------------------------
// K2 v3: per-edge pass, bf16 MFMA. 128 edges/block, 8 waves, CSR order +
// XCD swizzle. LDS 49.8KB -> 3 blocks/CU (was 71KB/2). Unpadded rows with
// XOR swizzle (byte ^= (row&7)<<4) -> uniform bank spread on b128 frags.
// W staged in two 64-row halves (nt 0-3 then 4-7), reusing one 16KB buffer.
// ---------------------------------------------------------------------------
__global__ __launch_bounds__(512, 6) void k_edge_mfma(
    const unsigned short* __restrict__ zb, const int* __restrict__ ei,
    const int* __restrict__ etype,
    const unsigned short* __restrict__ Wcb, const float* __restrict__ tvg,
    const float* __restrict__ eb1, const float* __restrict__ ew2,
    const float* __restrict__ eb2,
    const unsigned short* __restrict__ Ab, const unsigned short* __restrict__ Bb,
    const int* __restrict__ eid, const int* __restrict__ de_perm,
    float* __restrict__ wexp_perm)
{
  __shared__ unsigned short Xb[128 * 128];   // 32KB, swizzled
  __shared__ unsigned short Wb[64 * 128];    // 16KB, swizzled, 2-phase
  __shared__ unsigned short se[128], de[128];
  __shared__ unsigned char  tyg[128];

  const int t = threadIdx.x;
  // XCD swizzle (grid 4688 % 8 == 0 -> simple bijective form)
  const int nx = gridDim.x >> 3;
  const int sb = (blockIdx.x & 7) * nx + (blockIdx.x >> 3);
  const int e0 = sb * 128;

  if (t < 128) {
    int pos = e0 + t;
    if (pos < NE) {
      int e  = eid[pos];
      se[t]  = (unsigned short)ei[e];
      de[t]  = (unsigned short)de_perm[pos];
      tyg[t] = (unsigned char)etype[e];
    } else { se[t] = 0; de[t] = 0; tyg[t] = 0; }
  }
  // stage W half 0 (global rows 0..63)
#pragma unroll
  for (int it = 0; it < 2; ++it) {
    int f = it * 512 + t, row = f >> 4, c = f & 15;
    int a = (row * 256 + c * 16) ^ ((row & 7) << 4);
    *reinterpret_cast<bf16x8*>((char*)Wb + a) =
        *reinterpret_cast<const bf16x8*>(&Wcb[row * 128 + c * 8]);
  }
  __syncthreads();

  // stage X = |zb[src]-zb[dst]| (bf16 gathers, 256B/row)
#pragma unroll
  for (int it = 0; it < 8; ++it) {
    int f = it * 512 + t, r = f >> 5, c4 = f & 31;
    ushort4 a4 = *reinterpret_cast<const ushort4*>(&zb[(size_t)se[r] * D + c4 * 4]);
    ushort4 b4 = *reinterpret_cast<const ushort4*>(&zb[(size_t)de[r] * D + c4 * 4]);
    ushort4 v;
    v.x = f2bf(fabsf(bf2f(a4.x) - bf2f(b4.x)));
    v.y = f2bf(fabsf(bf2f(a4.y) - bf2f(b4.y)));
    v.z = f2bf(fabsf(bf2f(a4.z) - bf2f(b4.z)));
    v.w = f2bf(fabsf(bf2f(a4.w) - bf2f(b4.w)));
    int a = (r * 256 + c4 * 8) ^ ((r & 7) << 4);
    *reinterpret_cast<ushort4*>((char*)Xb + a) = v;
  }
  __syncthreads();

  const int l = t & 63, q = l >> 4, r = l & 15;
  const int me = (t >> 6) * 16;

  f32x4 acc[8];
#pragma unroll
  for (int nt = 0; nt < 8; ++nt) acc[nt] = (f32x4){0.f, 0.f, 0.f, 0.f};

  // phase 0: nt 0..3
#pragma unroll
  for (int ks = 0; ks < 4; ++ks) {
    int xa = ((me + r) * 256 + ks * 64 + q * 16) ^ ((r & 7) << 4);
    bf16x8 a = *reinterpret_cast<const bf16x8*>((const char*)Xb + xa);
#pragma unroll
    for (int ntl = 0; ntl < 4; ++ntl) {
      int wrow = ntl * 16 + r;
      int wa = (wrow * 256 + ks * 64 + q * 16) ^ ((wrow & 7) << 4);
      bf16x8 b = *reinterpret_cast<const bf16x8*>((const char*)Wb + wa);
      acc[ntl] = __builtin_amdgcn_mfma_f32_16x16x32_bf16(a, b, acc[ntl], 0, 0, 0);
    }
  }
  __syncthreads();   // all waves done reading W half 0

  // stage W half 1 (global rows 64..127)
#pragma unroll
  for (int it = 0; it < 2; ++it) {
    int f = it * 512 + t, row = f >> 4, c = f & 15;
    int a = (row * 256 + c * 16) ^ ((row & 7) << 4);
    *reinterpret_cast<bf16x8*>((char*)Wb + a) =
        *reinterpret_cast<const bf16x8*>(&Wcb[(64 + row) * 128 + c * 8]);
  }
  __syncthreads();

  // phase 1: nt 4..7
#pragma unroll
  for (int ks = 0; ks < 4; ++ks) {
    int xa = ((me + r) * 256 + ks * 64 + q * 16) ^ ((r & 7) << 4);
    bf16x8 a = *reinterpret_cast<const bf16x8*>((const char*)Xb + xa);
#pragma unroll
    for (int ntl = 0; ntl < 4; ++ntl) {
      int wrow = ntl * 16 + r;
      int wa = (wrow * 256 + ks * 64 + q * 16) ^ ((wrow & 7) << 4);
      bf16x8 b = *reinterpret_cast<const bf16x8*>((const char*)Wb + wa);
      acc[4 + ntl] = __builtin_amdgcn_mfma_f32_16x16x32_bf16(a, b, acc[4 + ntl], 0, 0, 0);
    }
  }

  // epilogue: finish h, dot with ew2, reduce over 16 col-lanes
  int s[4], dd[4], ty[4];
#pragma unroll
  for (int i = 0; i < 4; ++i) {
    int el = me + q * 4 + i;
    s[i] = se[el]; dd[i] = de[el]; ty[i] = tyg[el];
  }
  float p[4] = {0.f, 0.f, 0.f, 0.f};
#pragma unroll
  for (int nt = 0; nt < 8; ++nt) {
    int col = nt * 16 + r;
    float e1  = eb1[col], w2 = ew2[col];
    float tva = tvg[col], tvb = tvg[128 + col];
#pragma unroll
    for (int i = 0; i < 4; ++i) {
      float h = acc[nt][i] + bf2f(Ab[(size_t)s[i] * D + col])
              + bf2f(Bb[(size_t)dd[i] * D + col]) + (ty[i] ? tvb : tva) + e1;
      p[i] += fmaxf(h, 0.f) * w2;
    }
  }
#pragma unroll
  for (int m = 1; m < 16; m <<= 1) {
#pragma unroll
    for (int i = 0; i < 4; ++i) p[i] += __shfl_xor(p[i], m);
  }
  if (r == 0) {
    float b2 = eb2[0];
#pragma unroll
    for (int i = 0; i < 4; ++i) {
      int pos = e0 + me + q * 4 + i;
      if (pos < NE) {
        float w = 1.0f / (1.0f + expf(-(p[i] + b2)));  // sigmoid
        wexp_perm[pos] = expf(w);                      // w in (0,1): stable
      }
    }
  }
}

// ---------------------------------------------------------------------------
// K3: fused per-node aggregation + residual + LayerNorm (unchanged).
// ---------------------------------------------------------------------------
__global__ __launch_bounds__(256) void k_agg(
    const float* __restrict__ z, const float* __restrict__ wexp_perm,
    const unsigned short* __restrict__ Mb, const int* __restrict__ rowptr,
    const int* __restrict__ eid, const int* __restrict__ de_perm,
    const float* __restrict__ gamma, const float* __restrict__ beta,
    float* __restrict__ out, float* __restrict__ alpha_out)
{
  const int t = threadIdx.x;
  const int n = blockIdx.x * 4 + (t >> 6);
  const int l = t & 63;
  const int start = rowptr[n], end = rowptr[n + 1];

  float tot = 0.f;
  for (int base = start; base < end; base += 64) {
    if (base + l < end) tot += wexp_perm[base + l];
  }
#pragma unroll
  for (int off = 32; off; off >>= 1) tot += __shfl_xor(tot, off);
  const float inv = 1.0f / (tot + 1e-12f);

  float2 acc = make_float2(0.f, 0.f);
  for (int base = start; base < end; base += 64) {
    int cnt = min(64, end - base);
    int dd = 0;
    float al = 0.f;
    if (l < cnt) {
      int pos = base + l;
      al = wexp_perm[pos] * inv;
      dd = de_perm[pos];
      alpha_out[eid[pos]] = al;
    }
    for (int i = 0; i < cnt; ++i) {
      float a = __shfl(al, i);
      int   d = __shfl(dd, i);
      ushort2 m = *reinterpret_cast<const ushort2*>(&Mb[(size_t)d * D + l * 2]);
      acc.x = fmaf(a, bf2f(m.x), acc.x);
      acc.y = fmaf(a, bf2f(m.y), acc.y);
    }
  }

  float2 xz = *reinterpret_cast<const float2*>(&z[(size_t)n * D + l * 2]);
  float x0 = xz.x + acc.x, x1 = xz.y + acc.y;
  float s = x0 + x1;
#pragma unroll
  for (int off = 32; off; off >>= 1) s += __shfl_xor(s, off);
  const float mu = s * (1.0f / 128.0f);
  float d0 = x0 - mu, d1 = x1 - mu;
  float q = d0 * d0 + d1 * d1;
#pragma unroll
  for (int off = 32; off; off >>= 1) q += __shfl_xor(q, off);
  const float rstd = rsqrtf(q * (1.0f / 128.0f) + 1e-5f);
  float2 g = *reinterpret_cast<const float2*>(&gamma[l * 2]);
  float2 b = *reinterpret_cast<const float2*>(&beta[l * 2]);
  float2 o = make_float2(d0 * rstd * g.x + b.x, d1 * rstd * g.y + b.y);
  *reinterpret_cast<float2*>(&out[(size_t)n * D + l * 2]) = o;
}

// ---------------------------------------------------------------------------
extern "C" void kernel_launch(void* const* d_in, const int* in_sizes, int n_in,
                              void* d_out, int out_size, void* d_ws, size_t ws_size,
                              hipStream_t stream)
{
  const float* z        = (const float*)d_in[0];
  const int*   ei       = (const int*)d_in[1];   // [2,E]: src row, then dst row
  const int*   etype    = (const int*)d_in[2];
  const float* type_emb = (const float*)d_in[3];
  const float* ew1      = (const float*)d_in[4];
  const float* eb1      = (const float*)d_in[5];
  const float* ew2      = (const float*)d_in[6];
  const float* eb2      = (const float*)d_in[7];
  const float* mw1      = (const float*)d_in[8];
  const float* mb1      = (const float*)d_in[9];
  const float* mw2      = (const float*)d_in[10];
  const float* mb2      = (const float*)d_in[11];
  const float* gamma    = (const float*)d_in[12];
  const float* beta     = (const float*)d_in[13];

  // workspace (float-unit offsets):
  // Ab|Bb|Mb|zb (bf16) | wexp_perm | ints | bf16 weights | tvg | scan temps
  float*          ws        = (float*)d_ws;
  unsigned short* Ab        = (unsigned short*)(ws);
  unsigned short* Bb        = (unsigned short*)(ws + 3200000);
  unsigned short* Mb        = (unsigned short*)(ws + 6400000);
  unsigned short* zb        = (unsigned short*)(ws + 9600000);
  float*          wexp_perm = ws + 12800000;
  int*            deg       = (int*)(ws + 13400000);
  int*            rowptr    = deg + 50000;
  int*            cursor    = rowptr + 50004;
  int*            eid       = cursor + 50000;
  int*            de_perm   = eid + 600000;
  unsigned short* Wcb       = (unsigned short*)(ws + 14800000);
  float*          tvg       = ws + 14810000;
  unsigned short* Wab       = (unsigned short*)(ws + 14820000);
  unsigned short* Wbb       = (unsigned short*)(ws + 14830000);
  unsigned short* m1h       = (unsigned short*)(ws + 14840000);
  unsigned short* m1l       = (unsigned short*)(ws + 14850000);
  unsigned short* m2h       = (unsigned short*)(ws + 14860000);
  unsigned short* m2l       = (unsigned short*)(ws + 14870000);
  int*            pre       = (int*)(ws + 14880000);   // 50176 ints
  int*            bsum      = (int*)(ws + 14940000);   // 256
  int*            bbase     = (int*)(ws + 14941000);   // 256

  float* out       = (float*)d_out;
  float* alpha_out = out + (size_t)NN * D;

  hipMemsetAsync(deg, 0, 50000 * sizeof(int), stream);

  k_prep<<<64, 256, 0, stream>>>(ew1, type_emb, mw1, mw2,
                                 Wab, Wbb, Wcb, m1h, m1l, m2h, m2l, tvg);
  k_hist<<<(NE + 255) / 256, 256, 0, stream>>>(ei, deg);
  k_scan1<<<SNB, 256, 0, stream>>>(deg, pre, bsum);
  k_scan2<<<1, 256, 0, stream>>>(bsum, bbase);
  k_scan3<<<SNB, 256, 0, stream>>>(pre, bbase, rowptr, cursor);
  k_fill<<<(NE + 255) / 256, 256, 0, stream>>>(ei, cursor, eid, de_perm);
  k_node_mfma<<<(NN + 127) / 128, 512, 0, stream>>>(z, Wab, Wbb, m1h, m1l,
                                                    m2h, m2l, mb1, mb2,
                                                    Ab, Bb, Mb, zb);
  k_edge_mfma<<<(NE + 127) / 128, 512, 0, stream>>>(zb, ei, etype, Wcb, tvg,
                                                    eb1, ew2, eb2, Ab, Bb,
                                                    eid, de_perm, wexp_perm);
  k_agg<<<NN / 4, 256, 0, stream>>>(z, wexp_perm, Mb, rowptr, eid, de_perm,
                                    gamma, beta, out, alpha_out);
}